// Round 2
// baseline (460.716 us; speedup 1.0000x reference)
//
#include <hip/hip_runtime.h>
#include <hip/hip_bf16.h>
#include <math.h>

#define Bn 4
#define Sn 512
#define Dn 512
#define DINn 1024
#define Hn 16
#define Pn 64
#define RNn 128
#define DFFn 1368
#define BSn (Bn*Sn)

typedef __attribute__((ext_vector_type(8))) short short8;
typedef __attribute__((ext_vector_type(4))) float f32x4;

static __device__ __forceinline__ float bf2f(__hip_bfloat16 v) { return __bfloat162float(v); }
static __device__ __forceinline__ __hip_bfloat16 f2bf(float v) { return __float2bfloat16(v); }

// ---------------- transpose+cast: f32 [Rr x Cc] -> bf16 [Cc x Rr] ----------------
__global__ void transpose_kernel(const float* __restrict__ in,
                                 __hip_bfloat16* __restrict__ out, int Rr, int Cc) {
  __shared__ __hip_bfloat16 tile[32][33];
  int c0 = blockIdx.x * 32, r0 = blockIdx.y * 32;
  int tx = threadIdx.x, ty = threadIdx.y;
  for (int i = ty; i < 32; i += 8) {
    int r = r0 + i, cc = c0 + tx;
    tile[i][tx] = (r < Rr && cc < Cc) ? f2bf(in[(size_t)r * Cc + cc]) : f2bf(0.f);
  }
  __syncthreads();
  for (int i = ty; i < 32; i += 8) {
    int r = c0 + i, cc = r0 + tx;
    if (r < Cc && cc < Rr) out[(size_t)r * Rr + cc] = tile[tx][i];
  }
}

// ---------------- rmsnorm (f32 in) * mask -> bf16 + f32 ----------------
__global__ void rmsnorm1_kernel(const float* __restrict__ x,
                                const float* __restrict__ w,
                                const float* __restrict__ mask,
                                __hip_bfloat16* __restrict__ outb,
                                float* __restrict__ outf) {
  int row = blockIdx.x, t = threadIdx.x;
  const float* xr = x + (size_t)row * Dn;
  float v0 = xr[t], v1 = xr[t + 256];
  float ss = v0 * v0 + v1 * v1;
#pragma unroll
  for (int o = 32; o > 0; o >>= 1) ss += __shfl_down(ss, o);
  __shared__ float red[4];
  if ((t & 63) == 0) red[t >> 6] = ss;
  __syncthreads();
  float tot = red[0] + red[1] + red[2] + red[3];
  float sc = rsqrtf(tot * (1.f / Dn) + 1e-6f);
  sc *= mask[row];
  float o0 = v0 * sc * w[t], o1v = v1 * sc * w[t + 256];
  outb[(size_t)row * Dn + t] = f2bf(o0);
  outb[(size_t)row * Dn + t + 256] = f2bf(o1v);
  outf[(size_t)row * Dn + t] = o0;
  outf[(size_t)row * Dn + t + 256] = o1v;
}

// ---------------- rmsnorm (f32 in, no mask) -> bf16 ----------------
__global__ void rmsnorm2_kernel(const float* __restrict__ x,
                                const float* __restrict__ w,
                                __hip_bfloat16* __restrict__ out) {
  int row = blockIdx.x, t = threadIdx.x;
  const float* xr = x + (size_t)row * Dn;
  float v0 = xr[t], v1 = xr[t + 256];
  float ss = v0 * v0 + v1 * v1;
#pragma unroll
  for (int o = 32; o > 0; o >>= 1) ss += __shfl_down(ss, o);
  __shared__ float red[4];
  if ((t & 63) == 0) red[t >> 6] = ss;
  __syncthreads();
  float tot = red[0] + red[1] + red[2] + red[3];
  float sc = rsqrtf(tot * (1.f / Dn) + 1e-6f);
  out[(size_t)row * Dn + t] = f2bf(v0 * sc * w[t]);
  out[(size_t)row * Dn + t + 256] = f2bf(v1 * sc * w[t + 256]);
}

// ---------------- GEMM: C[M,N] f32 = A[M,K] bf16 @ (BT[N,K])^T bf16 ----------------
__global__ __launch_bounds__(256) void gemm_bf16_kernel(
    const __hip_bfloat16* __restrict__ A, const __hip_bfloat16* __restrict__ BT,
    float* __restrict__ C, int M, int N, int K) {
  __shared__ short As[128][40];
  __shared__ short Bs[128][40];
  int m0 = blockIdx.x * 128, n0 = blockIdx.y * 128;
  int t = threadIdx.x;
  int lane = t & 63, wv = t >> 6;
  int wm = (wv & 1) * 64, wn = (wv >> 1) * 64;
  f32x4 acc[4][4];
#pragma unroll
  for (int i = 0; i < 4; ++i)
#pragma unroll
    for (int j = 0; j < 4; ++j) acc[i][j] = (f32x4){0.f, 0.f, 0.f, 0.f};
  const short* Ag = (const short*)A;
  const short* Bg = (const short*)BT;
  int sr = t >> 2;
  int sc = (t & 3) * 8;
  int kTiles = (K + 31) >> 5;
  for (int kt = 0; kt < kTiles; ++kt) {
    int k0 = kt << 5;
    __syncthreads();
    bool kin = (k0 + sc) < K;  // K is a multiple of 8
    short8 a0 = 0, a1 = 0, b0 = 0, b1 = 0;
    if (kin) {
      a0 = *(const short8*)(Ag + (size_t)(m0 + sr) * K + k0 + sc);
      a1 = *(const short8*)(Ag + (size_t)(m0 + sr + 64) * K + k0 + sc);
      int rb0 = n0 + sr, rb1 = n0 + sr + 64;
      if (rb0 < N) b0 = *(const short8*)(Bg + (size_t)rb0 * K + k0 + sc);
      if (rb1 < N) b1 = *(const short8*)(Bg + (size_t)rb1 * K + k0 + sc);
    }
    *(short8*)&As[sr][sc] = a0;
    *(short8*)&As[sr + 64][sc] = a1;
    *(short8*)&Bs[sr][sc] = b0;
    *(short8*)&Bs[sr + 64][sc] = b1;
    __syncthreads();
    int fr = lane & 15, fq = (lane >> 4) * 8;
    short8 af[4], bfr[4];
#pragma unroll
    for (int i = 0; i < 4; ++i) af[i] = *(const short8*)&As[wm + i * 16 + fr][fq];
#pragma unroll
    for (int i = 0; i < 4; ++i) bfr[i] = *(const short8*)&Bs[wn + i * 16 + fr][fq];
#pragma unroll
    for (int mi = 0; mi < 4; ++mi)
#pragma unroll
      for (int ni = 0; ni < 4; ++ni)
        acc[mi][ni] = __builtin_amdgcn_mfma_f32_16x16x32_bf16(af[mi], bfr[ni], acc[mi][ni], 0, 0, 0);
  }
  int fr = lane & 15, fq4 = (lane >> 4) * 4;
#pragma unroll
  for (int mi = 0; mi < 4; ++mi)
#pragma unroll
    for (int ni = 0; ni < 4; ++ni) {
      int col = n0 + wn + ni * 16 + fr;
      if (col < N) {
        int rowb = m0 + wm + mi * 16 + fq4;
#pragma unroll
        for (int r = 0; r < 4; ++r) C[(size_t)(rowb + r) * N + col] = acc[mi][ni][r];
      }
    }
}

// ---------------- dt = softplus(xn @ Wdt + bias); a = exp(-exp(A_log)*dt) ----------------
__global__ void dt_kernel(const float* __restrict__ xnf,
                          const float* __restrict__ Wdt,
                          const float* __restrict__ dtb,
                          const float* __restrict__ Alog,
                          float* __restrict__ dt, float* __restrict__ aa) {
  __shared__ float xs[Dn];
  int row = blockIdx.x, t = threadIdx.x;
  xs[t] = xnf[(size_t)row * Dn + t];
  xs[t + 256] = xnf[(size_t)row * Dn + t + 256];
  __syncthreads();
  int h = t >> 4, j = t & 15;
  float s = 0.f;
  for (int k = j * 32; k < j * 32 + 32; ++k) s = fmaf(xs[k], Wdt[k * Hn + h], s);
#pragma unroll
  for (int o = 8; o > 0; o >>= 1) s += __shfl_down(s, o, 16);
  if (j == 0) {
    float v = s + dtb[h];
    float sp = (v > 20.f) ? v : log1pf(expf(v));
    float Ah = expf(Alog[h]);
    dt[(size_t)row * Hn + h] = sp;
    aa[(size_t)row * Hn + h] = expf(-Ah * sp);
  }
}

// ---------------- sequential SSM scan ----------------
// block = (b,h); 512 threads = 8 waves; wave w owns rn in [16w,16w+16), lane = p.
__global__ __launch_bounds__(512) void scan_kernel(
    const float* __restrict__ Bm, const float* __restrict__ Cm,
    const float* __restrict__ u, const float* __restrict__ dt,
    const float* __restrict__ aa, float* __restrict__ ys) {
  int b = blockIdx.x >> 4, h = blockIdx.x & 15;
  int t = threadIdx.x;
  int wv = t >> 6, lane = t & 63;
  __shared__ __align__(16) float sB[16][RNn];
  __shared__ __align__(16) float sC[16][RNn];
  __shared__ __align__(16) float su[16][Pn];
  __shared__ float sa[16];
  __shared__ float sdt[16];
  __shared__ __align__(16) float yc[16][8][Pn];
  float hreg[16];
#pragma unroll
  for (int j = 0; j < 16; ++j) hreg[j] = 0.f;
  int tt5 = t >> 5, q4 = (t & 31) * 4;
  int tu = t >> 4, qu = (t & 15) * 4;
  for (int c = 0; c < Sn / 16; ++c) {
    int s0 = c * 16;
    __syncthreads();
    {
      size_t rb = ((size_t)((b * Sn + s0 + tt5) * Hn + h)) * RNn + q4;
      *(f32x4*)&sB[tt5][q4] = *(const f32x4*)(Bm + rb);
      *(f32x4*)&sC[tt5][q4] = *(const f32x4*)(Cm + rb);
      if (t < 256) {
        size_t ru = (size_t)(b * Sn + s0 + tu) * DINn + h * Pn + qu;
        *(f32x4*)&su[tu][qu] = *(const f32x4*)(u + ru);
      }
      if (t < 16) sa[t] = aa[(size_t)(b * Sn + s0 + t) * Hn + h];
      else if (t < 32) sdt[t - 16] = dt[(size_t)(b * Sn + s0 + (t - 16)) * Hn + h];
    }
    __syncthreads();
#pragma unroll 1
    for (int st = 0; st < 16; ++st) {
      float a_t = sa[st];
      float udp = su[st][lane] * sdt[st];
      float ysum = 0.f;
      const float* Brow = &sB[st][wv * 16];
      const float* Crow = &sC[st][wv * 16];
#pragma unroll
      for (int j = 0; j < 16; ++j) {
        float hv = fmaf(a_t, hreg[j], Brow[j] * udp);
        hreg[j] = hv;
        ysum = fmaf(Crow[j], hv, ysum);
      }
      yc[st][wv][lane] = ysum;
    }
    __syncthreads();
#pragma unroll
    for (int rep = 0; rep < 2; ++rep) {
      int ttw = (t >> 6) + rep * 8;
      float sum = 0.f;
#pragma unroll
      for (int w = 0; w < 8; ++w) sum += yc[ttw][w][lane];
      ys[(size_t)(b * Sn + s0 + ttw) * DINn + h * Pn + lane] = sum;
    }
  }
}

// ---------------- y2 = (ys + u*D_skip) * silu(z) -> bf16 ----------------
__global__ void gate_kernel(const float* __restrict__ ys, const float* __restrict__ u,
                            const float* __restrict__ z, const float* __restrict__ Dsk,
                            __hip_bfloat16* __restrict__ y2b) {
  int base = (blockIdx.x * 256 + threadIdx.x) * 4;
  f32x4 yv = *(const f32x4*)(ys + base);
  f32x4 uv = *(const f32x4*)(u + base);
  f32x4 zv = *(const f32x4*)(z + base);
  int h = (base & (DINn - 1)) >> 6;
  float dsk = Dsk[h];
#pragma unroll
  for (int j = 0; j < 4; ++j) {
    float zz = zv[j];
    float sil = zz / (1.f + expf(-zz));
    y2b[base + j] = f2bf((yv[j] + uv[j] * dsk) * sil);
  }
}

// ---------------- xres = x + o1*mask (f32 out) ----------------
__global__ void resid_kernel(const float* __restrict__ x, const float* __restrict__ o1,
                             const float* __restrict__ mask, float* __restrict__ xres) {
  int base = (blockIdx.x * 256 + threadIdx.x) * 4;
  int row = base >> 9;
  float m = mask[row];
  f32x4 ov = *(const f32x4*)(o1 + base);
  f32x4 xv = *(const f32x4*)(x + base);
#pragma unroll
  for (int j = 0; j < 4; ++j) xres[base + j] = xv[j] + ov[j] * m;
}

// ---------------- gated = silu(h1)*h3 -> bf16 ----------------
__global__ void ffngate_kernel(const float* __restrict__ h1, const float* __restrict__ h3,
                               __hip_bfloat16* __restrict__ g) {
  int base = (blockIdx.x * 256 + threadIdx.x) * 4;
  f32x4 a = *(const f32x4*)(h1 + base);
  f32x4 b3 = *(const f32x4*)(h3 + base);
#pragma unroll
  for (int j = 0; j < 4; ++j) {
    float v = a[j];
    float sil = v / (1.f + expf(-v));
    g[base + j] = f2bf(sil * b3[j]);
  }
}

// ---------------- out = (xres + o2) * mask -> f32 ----------------
__global__ void final_kernel(const float* __restrict__ xres, const float* __restrict__ o2,
                             const float* __restrict__ mask,
                             float* __restrict__ out) {
  int base = (blockIdx.x * 256 + threadIdx.x) * 4;
  int row = base >> 9;
  float m = mask[row];
  f32x4 xv = *(const f32x4*)(xres + base);
  f32x4 ov = *(const f32x4*)(o2 + base);
#pragma unroll
  for (int j = 0; j < 4; ++j) out[base + j] = (xv[j] + ov[j]) * m;
}

extern "C" void kernel_launch(void* const* d_in, const int* in_sizes, int n_in,
                              void* d_out, int out_size, void* d_ws, size_t ws_size,
                              hipStream_t stream) {
  const float* x    = (const float*)d_in[0];
  const float* mask = (const float*)d_in[1];
  const float* n1w  = (const float*)d_in[2];
  const float* n2w  = (const float*)d_in[3];
  const float* Wz   = (const float*)d_in[4];
  const float* Wx   = (const float*)d_in[5];
  const float* Wb   = (const float*)d_in[6];
  const float* Wc   = (const float*)d_in[7];
  const float* Wdt  = (const float*)d_in[8];
  const float* dtb  = (const float*)d_in[9];
  const float* Alog = (const float*)d_in[10];
  const float* Dsk  = (const float*)d_in[11];
  const float* Wout = (const float*)d_in[12];
  const float* w1   = (const float*)d_in[13];
  const float* w2   = (const float*)d_in[14];
  const float* w3   = (const float*)d_in[15];

  char* ws = (char*)d_ws;
  size_t off = 0;
  auto alloc = [&](size_t bytes) {
    char* p = ws + off;
    off += (bytes + 255) & ~(size_t)255;
    return p;
  };
  __hip_bfloat16* xnb = (__hip_bfloat16*)alloc((size_t)BSn * Dn * 2);
  float* xnf = (float*)alloc((size_t)BSn * Dn * 4);
  float* z   = (float*)alloc((size_t)BSn * DINn * 4);
  float* u   = (float*)alloc((size_t)BSn * DINn * 4);
  float* Bm  = (float*)alloc((size_t)BSn * 2048 * 4);
  float* Cm  = (float*)alloc((size_t)BSn * 2048 * 4);
  float* dt  = (float*)alloc((size_t)BSn * Hn * 4);
  float* aa  = (float*)alloc((size_t)BSn * Hn * 4);
  float* ys  = (float*)alloc((size_t)BSn * DINn * 4);
  __hip_bfloat16* y2b = (__hip_bfloat16*)alloc((size_t)BSn * DINn * 2);
  float* o1  = (float*)alloc((size_t)BSn * Dn * 4);
  float* xres = (float*)alloc((size_t)BSn * Dn * 4);
  __hip_bfloat16* WzT   = (__hip_bfloat16*)alloc((size_t)DINn * Dn * 2);
  __hip_bfloat16* WxT   = (__hip_bfloat16*)alloc((size_t)DINn * Dn * 2);
  __hip_bfloat16* WbT   = (__hip_bfloat16*)alloc((size_t)2048 * Dn * 2);
  __hip_bfloat16* WcT   = (__hip_bfloat16*)alloc((size_t)2048 * Dn * 2);
  __hip_bfloat16* WoutT = (__hip_bfloat16*)alloc((size_t)Dn * DINn * 2);
  __hip_bfloat16* w1T   = (__hip_bfloat16*)alloc((size_t)DFFn * Dn * 2);
  __hip_bfloat16* w3T   = (__hip_bfloat16*)alloc((size_t)DFFn * Dn * 2);
  __hip_bfloat16* w2T   = (__hip_bfloat16*)alloc((size_t)Dn * DFFn * 2);
  // reuse (lifetimes disjoint):
  float* h1 = Bm;   // BSn*DFF f32 = 11.2MB < 16MB
  float* h3 = Cm;
  __hip_bfloat16* gatedb = (__hip_bfloat16*)z;  // 5.6MB < 8MB
  float* o2 = u;    // 4MB < 8MB

  dim3 tb(32, 8);
  transpose_kernel<<<dim3(32, 16), tb, 0, stream>>>(Wz, WzT, 512, 1024);
  transpose_kernel<<<dim3(32, 16), tb, 0, stream>>>(Wx, WxT, 512, 1024);
  transpose_kernel<<<dim3(64, 16), tb, 0, stream>>>(Wb, WbT, 512, 2048);
  transpose_kernel<<<dim3(64, 16), tb, 0, stream>>>(Wc, WcT, 512, 2048);
  transpose_kernel<<<dim3(16, 32), tb, 0, stream>>>(Wout, WoutT, 1024, 512);
  transpose_kernel<<<dim3(43, 16), tb, 0, stream>>>(w1, w1T, 512, 1368);
  transpose_kernel<<<dim3(43, 16), tb, 0, stream>>>(w3, w3T, 512, 1368);
  transpose_kernel<<<dim3(16, 43), tb, 0, stream>>>(w2, w2T, 1368, 512);

  rmsnorm1_kernel<<<BSn, 256, 0, stream>>>(x, n1w, mask, xnb, xnf);
  gemm_bf16_kernel<<<dim3(16, 8), 256, 0, stream>>>(xnb, WzT, z, BSn, DINn, Dn);
  gemm_bf16_kernel<<<dim3(16, 8), 256, 0, stream>>>(xnb, WxT, u, BSn, DINn, Dn);
  gemm_bf16_kernel<<<dim3(16, 16), 256, 0, stream>>>(xnb, WbT, Bm, BSn, 2048, Dn);
  gemm_bf16_kernel<<<dim3(16, 16), 256, 0, stream>>>(xnb, WcT, Cm, BSn, 2048, Dn);
  dt_kernel<<<BSn, 256, 0, stream>>>(xnf, Wdt, dtb, Alog, dt, aa);
  scan_kernel<<<64, 512, 0, stream>>>(Bm, Cm, u, dt, aa, ys);
  gate_kernel<<<2048, 256, 0, stream>>>(ys, u, z, Dsk, y2b);
  gemm_bf16_kernel<<<dim3(16, 4), 256, 0, stream>>>(y2b, WoutT, o1, BSn, Dn, DINn);
  resid_kernel<<<1024, 256, 0, stream>>>(x, o1, mask, xres);
  rmsnorm2_kernel<<<BSn, 256, 0, stream>>>(xres, n2w, xnb);
  gemm_bf16_kernel<<<dim3(16, 11), 256, 0, stream>>>(xnb, w1T, h1, BSn, DFFn, Dn);
  gemm_bf16_kernel<<<dim3(16, 11), 256, 0, stream>>>(xnb, w3T, h3, BSn, DFFn, Dn);
  ffngate_kernel<<<2736, 256, 0, stream>>>(h1, h3, gatedb);
  gemm_bf16_kernel<<<dim3(16, 4), 256, 0, stream>>>(gatedb, w2T, o2, BSn, Dn, DFFn);
  final_kernel<<<1024, 256, 0, stream>>>(xres, o2, mask, (float*)d_out);
}

// Round 3
// 352.455 us; speedup vs baseline: 1.3072x; 1.3072x over previous
//
#include <hip/hip_runtime.h>
#include <hip/hip_bf16.h>
#include <math.h>
#include <type_traits>

#define Bn 4
#define Sn 512
#define Dn 512
#define DINn 1024
#define Hn 16
#define Pn 64
#define RNn 128
#define DFFn 1368
#define BSn (Bn*Sn)
#define CH 64
#define NCH (Sn/CH)   // 8

typedef __attribute__((ext_vector_type(8))) short short8;
typedef __attribute__((ext_vector_type(4))) float f32x4;

static __device__ __forceinline__ float bf2f(__hip_bfloat16 v){return __bfloat162float(v);}
static __device__ __forceinline__ __hip_bfloat16 f2bf(float v){return __float2bfloat16(v);}
static __device__ __forceinline__ short f2bfs(float v){ __hip_bfloat16 b=f2bf(v); short s; __builtin_memcpy(&s,&b,2); return s; }
static __device__ __forceinline__ float bfs2f(short s){ __hip_bfloat16 b; __builtin_memcpy(&b,&s,2); return bf2f(b); }

// ---------------- transpose+cast: f32 [Rr x Cc] -> bf16 [Cc x Rr] ----------------
__global__ void transpose_kernel(const float* __restrict__ in,
                                 __hip_bfloat16* __restrict__ out, int Rr, int Cc) {
  __shared__ __hip_bfloat16 tile[32][33];
  int c0 = blockIdx.x * 32, r0 = blockIdx.y * 32;
  int tx = threadIdx.x, ty = threadIdx.y;
  for (int i = ty; i < 32; i += 8) {
    int r = r0 + i, cc = c0 + tx;
    tile[i][tx] = (r < Rr && cc < Cc) ? f2bf(in[(size_t)r * Cc + cc]) : f2bf(0.f);
  }
  __syncthreads();
  for (int i = ty; i < 32; i += 8) {
    int r = c0 + i, cc = r0 + tx;
    if (r < Cc && cc < Rr) out[(size_t)r * Rr + cc] = tile[tx][i];
  }
}

// ---------------- rmsnorm (f32 in) * mask -> bf16 + f32 ----------------
__global__ void rmsnorm1_kernel(const float* __restrict__ x,
                                const float* __restrict__ w,
                                const float* __restrict__ mask,
                                __hip_bfloat16* __restrict__ outb,
                                float* __restrict__ outf) {
  int row = blockIdx.x, t = threadIdx.x;
  const float* xr = x + (size_t)row * Dn;
  float v0 = xr[t], v1 = xr[t + 256];
  float ss = v0 * v0 + v1 * v1;
#pragma unroll
  for (int o = 32; o > 0; o >>= 1) ss += __shfl_down(ss, o);
  __shared__ float red[4];
  if ((t & 63) == 0) red[t >> 6] = ss;
  __syncthreads();
  float tot = red[0] + red[1] + red[2] + red[3];
  float sc = rsqrtf(tot * (1.f / Dn) + 1e-6f);
  sc *= mask[row];
  float o0 = v0 * sc * w[t], o1v = v1 * sc * w[t + 256];
  outb[(size_t)row * Dn + t] = f2bf(o0);
  outb[(size_t)row * Dn + t + 256] = f2bf(o1v);
  outf[(size_t)row * Dn + t] = o0;
  outf[(size_t)row * Dn + t + 256] = o1v;
}

// ---------------- rmsnorm (f32 in, no mask) -> bf16 ----------------
__global__ void rmsnorm2_kernel(const float* __restrict__ x,
                                const float* __restrict__ w,
                                __hip_bfloat16* __restrict__ out) {
  int row = blockIdx.x, t = threadIdx.x;
  const float* xr = x + (size_t)row * Dn;
  float v0 = xr[t], v1 = xr[t + 256];
  float ss = v0 * v0 + v1 * v1;
#pragma unroll
  for (int o = 32; o > 0; o >>= 1) ss += __shfl_down(ss, o);
  __shared__ float red[4];
  if ((t & 63) == 0) red[t >> 6] = ss;
  __syncthreads();
  float tot = red[0] + red[1] + red[2] + red[3];
  float sc = rsqrtf(tot * (1.f / Dn) + 1e-6f);
  out[(size_t)row * Dn + t] = f2bf(v0 * sc * w[t]);
  out[(size_t)row * Dn + t + 256] = f2bf(v1 * sc * w[t + 256]);
}

// ---------------- GEMM: C[M,N] = A[M,K] bf16 @ (BT[N,K])^T bf16, OT in {f32,bf16} ----------------
template <typename OT>
__global__ __launch_bounds__(256) void gemm_kernel(
    const __hip_bfloat16* __restrict__ A, const __hip_bfloat16* __restrict__ BT,
    OT* __restrict__ C, int M, int N, int K) {
  __shared__ short As[128][40];
  __shared__ short Bs[128][40];
  int m0 = blockIdx.x * 128, n0 = blockIdx.y * 128;
  int t = threadIdx.x;
  int lane = t & 63, wv = t >> 6;
  int wm = (wv & 1) * 64, wn = (wv >> 1) * 64;
  f32x4 acc[4][4];
#pragma unroll
  for (int i = 0; i < 4; ++i)
#pragma unroll
    for (int j = 0; j < 4; ++j) acc[i][j] = (f32x4){0.f, 0.f, 0.f, 0.f};
  const short* Ag = (const short*)A;
  const short* Bg = (const short*)BT;
  int sr = t >> 2;
  int sc = (t & 3) * 8;
  int kTiles = (K + 31) >> 5;
  for (int kt = 0; kt < kTiles; ++kt) {
    int k0 = kt << 5;
    __syncthreads();
    bool kin = (k0 + sc) < K;
    short8 a0 = 0, a1 = 0, b0 = 0, b1 = 0;
    if (kin) {
      a0 = *(const short8*)(Ag + (size_t)(m0 + sr) * K + k0 + sc);
      a1 = *(const short8*)(Ag + (size_t)(m0 + sr + 64) * K + k0 + sc);
      int rb0 = n0 + sr, rb1 = n0 + sr + 64;
      if (rb0 < N) b0 = *(const short8*)(Bg + (size_t)rb0 * K + k0 + sc);
      if (rb1 < N) b1 = *(const short8*)(Bg + (size_t)rb1 * K + k0 + sc);
    }
    *(short8*)&As[sr][sc] = a0;
    *(short8*)&As[sr + 64][sc] = a1;
    *(short8*)&Bs[sr][sc] = b0;
    *(short8*)&Bs[sr + 64][sc] = b1;
    __syncthreads();
    int fr = lane & 15, fq = (lane >> 4) * 8;
    short8 af[4], bfr[4];
#pragma unroll
    for (int i = 0; i < 4; ++i) af[i] = *(const short8*)&As[wm + i * 16 + fr][fq];
#pragma unroll
    for (int i = 0; i < 4; ++i) bfr[i] = *(const short8*)&Bs[wn + i * 16 + fr][fq];
#pragma unroll
    for (int mi = 0; mi < 4; ++mi)
#pragma unroll
      for (int ni = 0; ni < 4; ++ni)
        acc[mi][ni] = __builtin_amdgcn_mfma_f32_16x16x32_bf16(af[mi], bfr[ni], acc[mi][ni], 0, 0, 0);
  }
  int fr = lane & 15, fq4 = (lane >> 4) * 4;
#pragma unroll
  for (int mi = 0; mi < 4; ++mi)
#pragma unroll
    for (int ni = 0; ni < 4; ++ni) {
      int col = n0 + wn + ni * 16 + fr;
      if (col < N) {
        int rowb = m0 + wm + mi * 16 + fq4;
#pragma unroll
        for (int r = 0; r < 4; ++r) {
          if constexpr (std::is_same<OT, float>::value)
            C[(size_t)(rowb + r) * N + col] = acc[mi][ni][r];
          else
            C[(size_t)(rowb + r) * N + col] = f2bf(acc[mi][ni][r]);
        }
      }
    }
}

// ---------------- dt = softplus(xn @ Wdt + bias); la = -exp(A_log)*dt ----------------
__global__ void dt_kernel(const float* __restrict__ xnf,
                          const float* __restrict__ Wdt,
                          const float* __restrict__ dtb,
                          const float* __restrict__ Alog,
                          float* __restrict__ dt, float* __restrict__ la) {
  __shared__ float xs[Dn];
  int row = blockIdx.x, t = threadIdx.x;
  xs[t] = xnf[(size_t)row * Dn + t];
  xs[t + 256] = xnf[(size_t)row * Dn + t + 256];
  __syncthreads();
  int h = t >> 4, j = t & 15;
  float s = 0.f;
  for (int k = j * 32; k < j * 32 + 32; ++k) s = fmaf(xs[k], Wdt[k * Hn + h], s);
#pragma unroll
  for (int o = 8; o > 0; o >>= 1) s += __shfl_down(s, o, 16);
  if (j == 0) {
    float v = s + dtb[h];
    float sp = (v > 20.f) ? v : log1pf(expf(v));
    float Ah = expf(Alog[h]);
    dt[(size_t)row * Hn + h] = sp;
    la[(size_t)row * Hn + h] = -Ah * sp;
  }
}

// ---------------- chunked scan: intra-chunk + chunk-state ----------------
// block = (b, c, h); 256 threads = 4 waves.
__global__ __launch_bounds__(256) void chunk_intra_kernel(
    const __hip_bfloat16* __restrict__ Bg, const __hip_bfloat16* __restrict__ Cg,
    const __hip_bfloat16* __restrict__ ug, const float* __restrict__ dt,
    const float* __restrict__ la, float* __restrict__ ys,
    float* __restrict__ Sbuf, float* __restrict__ ecL, float* __restrict__ ec) {
  int id = blockIdx.x;
  int h = id & 15, c = (id >> 4) & 7, b = id >> 7;
  int t = threadIdx.x, lane = t & 63, wv = t >> 6;
  __shared__ __align__(16) char smem[55040];
  short* sCB = (short*)smem;             // sC [64][136] (phase<=3a), sBt [128][72] (phase>=3b)
  short* sB  = (short*)(smem + 18432);   // [64][136]
  short* sUD = (short*)(smem + 35840);   // [64 p][72]  (s-minor)
  short* sG  = (short*)(smem + 45056);   // [64 t][72]  (s-minor)
  float* scum = (float*)(smem + 54272);  // [64]
  float* sws  = scum + 64;               // exp(cum63-cum[s])
  float* sdt  = sws + 64;
  int row0 = b * Sn + c * CH;
  // phase1: stage C,B (bf16), dt, la
#pragma unroll
  for (int i = 0; i < 4; ++i) {
    int idx = t + i * 256;               // 0..1023
    int r = idx >> 4, kc = (idx & 15) * 8;
    *(short8*)&sCB[r * 136 + kc] = *(const short8*)((const short*)Cg + (size_t)(row0 + r) * 2048 + h * 128 + kc);
    *(short8*)&sB [r * 136 + kc] = *(const short8*)((const short*)Bg + (size_t)(row0 + r) * 2048 + h * 128 + kc);
  }
  if (t < 64) { sdt[t] = dt[(size_t)(row0 + t) * Hn + h]; scum[t] = la[(size_t)(row0 + t) * Hn + h]; }
  __syncthreads();
  // phase2: wave0 log-space prefix; all waves build sUD (transposed u*dt)
  if (wv == 0) {
    float v = scum[lane];
#pragma unroll
    for (int o = 1; o < 64; o <<= 1) { float n = __shfl_up(v, o); if (lane >= o) v += n; }
    scum[lane] = v;
    float c63 = __shfl(v, 63);
    sws[lane] = __expf(c63 - v);
    ec[((size_t)((b * NCH + c) * Hn + h)) * 64 + lane] = __expf(v);
    if (lane == 0) ecL[(b * NCH + c) * Hn + h] = __expf(c63);
  }
#pragma unroll
  for (int i = 0; i < 2; ++i) {
    int idx = t + i * 256;               // 0..511
    int s = idx >> 3, pc = (idx & 7) * 8;
    short8 uv = *(const short8*)((const short*)ug + (size_t)(row0 + s) * DINn + h * 64 + pc);
    float dv = sdt[s];
#pragma unroll
    for (int j = 0; j < 8; ++j) sUD[(pc + j) * 72 + s] = f2bfs(bfs2f(uv[j]) * dv);
  }
  __syncthreads();
  int fr = lane & 15, fq = (lane >> 4) * 8, q4 = (lane >> 4) * 4;
  // phase3a: G0 = C @ B^T (K=128), decay-mask, store bf16 sG
  {
    short8 af[4];
#pragma unroll
    for (int k = 0; k < 4; ++k) af[k] = *(short8*)&sCB[(16 * wv + fr) * 136 + k * 32 + fq];
#pragma unroll
    for (int j = 0; j < 4; ++j) {
      f32x4 acc = (f32x4){0.f, 0.f, 0.f, 0.f};
#pragma unroll
      for (int k = 0; k < 4; ++k) {
        short8 bf = *(short8*)&sB[(16 * j + fr) * 136 + k * 32 + fq];
        acc = __builtin_amdgcn_mfma_f32_16x16x32_bf16(af[k], bf, acc, 0, 0, 0);
      }
      int ss = 16 * j + fr;
      float cs = scum[ss];
#pragma unroll
      for (int r = 0; r < 4; ++r) {
        int tt = 16 * wv + q4 + r;
        float w = (ss <= tt) ? __expf(scum[tt] - cs) : 0.f;
        sG[tt * 72 + ss] = f2bfs(acc[r] * w);
      }
    }
  }
  __syncthreads();
  // phase3b: sBt[rn][s] = B[s][rn]*exp(cum63-cum[s])  (overwrites sC region)
#pragma unroll
  for (int i = 0; i < 32; ++i) {
    int idx = t + i * 256;
    int rn = idx >> 6, s = idx & 63;
    sCB[rn * 72 + s] = f2bfs(bfs2f(sB[s * 136 + rn]) * sws[s]);
  }
  __syncthreads();
  // phase4a: Y_intra = G @ UD  (M=64 t, N=64 p, K=64 s)
  {
    short8 ag[2];
#pragma unroll
    for (int k = 0; k < 2; ++k) ag[k] = *(short8*)&sG[(16 * wv + fr) * 72 + k * 32 + fq];
#pragma unroll
    for (int j = 0; j < 4; ++j) {
      f32x4 acc = (f32x4){0.f, 0.f, 0.f, 0.f};
#pragma unroll
      for (int k = 0; k < 2; ++k) {
        short8 bf = *(short8*)&sUD[(16 * j + fr) * 72 + k * 32 + fq];
        acc = __builtin_amdgcn_mfma_f32_16x16x32_bf16(ag[k], bf, acc, 0, 0, 0);
      }
#pragma unroll
      for (int r = 0; r < 4; ++r)
        ys[(size_t)(row0 + 16 * wv + q4 + r) * DINn + h * 64 + 16 * j + fr] = acc[r];
    }
  }
  // phase4b: S_c = Bt @ UD  (M=128 rn, N=64 p, K=64 s)
#pragma unroll
  for (int mt0 = 0; mt0 < 2; ++mt0) {
    int mt = wv * 2 + mt0;
    short8 ab[2];
#pragma unroll
    for (int k = 0; k < 2; ++k) ab[k] = *(short8*)&sCB[(16 * mt + fr) * 72 + k * 32 + fq];
#pragma unroll
    for (int j = 0; j < 4; ++j) {
      f32x4 acc = (f32x4){0.f, 0.f, 0.f, 0.f};
#pragma unroll
      for (int k = 0; k < 2; ++k) {
        short8 bf = *(short8*)&sUD[(16 * j + fr) * 72 + k * 32 + fq];
        acc = __builtin_amdgcn_mfma_f32_16x16x32_bf16(ab[k], bf, acc, 0, 0, 0);
      }
#pragma unroll
      for (int r = 0; r < 4; ++r)
        Sbuf[((size_t)((b * NCH + c) * Hn + h) * RNn + 16 * mt + q4 + r) * 64 + 16 * j + fr] = acc[r];
    }
  }
}

// ---------------- prefix over chunk states (8 sequential steps, fully parallel elsewhere) ----------------
__global__ void chunk_state_kernel(const float* __restrict__ Sbuf, const float* __restrict__ ecL,
                                   float* __restrict__ Hp) {
  int bh = blockIdx.x >> 5;                          // 64 (b,h) pairs
  int j = (blockIdx.x & 31) * 256 + threadIdx.x;     // 0..8191 = rn*64+p
  int b = bh >> 4, h = bh & 15;
  float hp = 0.f;
#pragma unroll
  for (int c = 0; c < NCH; ++c) {
    size_t addr = ((size_t)((b * NCH + c) * Hn + h)) * 8192 + j;
    Hp[addr] = hp;
    hp = ecL[(b * NCH + c) * Hn + h] * hp + Sbuf[addr];
  }
}

// ---------------- inter-chunk: ys += ecum[t] * (C @ H_prefix) ----------------
__global__ __launch_bounds__(256) void chunk_inter_kernel(
    const __hip_bfloat16* __restrict__ Cg, const float* __restrict__ Hp,
    const float* __restrict__ ec, float* __restrict__ ys) {
  int id = blockIdx.x;
  int h = id & 15, c = (id >> 4) & 7, b = id >> 7;
  if (c == 0) return;                                // Hp==0 for first chunk
  int t = threadIdx.x, lane = t & 63, wv = t >> 6;
  __shared__ __align__(16) short sC[64 * 136];
  __shared__ __align__(16) short sHt[64 * 136];      // [p][rn]
  __shared__ float sec[64];
  int row0 = b * Sn + c * CH;
  size_t hbase = ((size_t)((b * NCH + c) * Hn + h)) * 8192;
#pragma unroll
  for (int i = 0; i < 4; ++i) {
    int idx = t + i * 256;
    int r = idx >> 4, kc = (idx & 15) * 8;
    *(short8*)&sC[r * 136 + kc] = *(const short8*)((const short*)Cg + (size_t)(row0 + r) * 2048 + h * 128 + kc);
  }
#pragma unroll
  for (int i = 0; i < 32; ++i) {
    int idx = t + i * 256;
    int rn = idx >> 6, p = idx & 63;
    sHt[p * 136 + rn] = f2bfs(Hp[hbase + idx]);
  }
  if (t < 64) sec[t] = ec[((size_t)((b * NCH + c) * Hn + h)) * 64 + t];
  __syncthreads();
  int fr = lane & 15, fq = (lane >> 4) * 8, q4 = (lane >> 4) * 4;
  short8 af[4];
#pragma unroll
  for (int k = 0; k < 4; ++k) af[k] = *(short8*)&sC[(16 * wv + fr) * 136 + k * 32 + fq];
#pragma unroll
  for (int j = 0; j < 4; ++j) {
    f32x4 acc = (f32x4){0.f, 0.f, 0.f, 0.f};
#pragma unroll
    for (int k = 0; k < 4; ++k) {
      short8 bf = *(short8*)&sHt[(16 * j + fr) * 136 + k * 32 + fq];
      acc = __builtin_amdgcn_mfma_f32_16x16x32_bf16(af[k], bf, acc, 0, 0, 0);
    }
#pragma unroll
    for (int r = 0; r < 4; ++r) {
      int tt = 16 * wv + q4 + r;
      size_t a = (size_t)(row0 + tt) * DINn + h * 64 + 16 * j + fr;
      ys[a] += sec[tt] * acc[r];
    }
  }
}

// ---------------- y2 = (ys + u*D_skip) * silu(z) -> bf16 ----------------
__global__ void gate_kernel(const float* __restrict__ ys, const __hip_bfloat16* __restrict__ ub,
                            const __hip_bfloat16* __restrict__ zb, const float* __restrict__ Dsk,
                            __hip_bfloat16* __restrict__ y2b) {
  int base = (blockIdx.x * 256 + threadIdx.x) * 8;
  short8 uv = *(const short8*)((const short*)ub + base);
  short8 zv = *(const short8*)((const short*)zb + base);
  int h = (base & (DINn - 1)) >> 6;
  float dsk = Dsk[h];
#pragma unroll
  for (int j = 0; j < 8; ++j) {
    float zz = bfs2f(zv[j]);
    float sil = zz / (1.f + __expf(-zz));
    y2b[base + j] = f2bf((ys[base + j] + bfs2f(uv[j]) * dsk) * sil);
  }
}

// ---------------- xres = x + o1*mask (f32 out) ----------------
__global__ void resid_kernel(const float* __restrict__ x, const float* __restrict__ o1,
                             const float* __restrict__ mask, float* __restrict__ xres) {
  int base = (blockIdx.x * 256 + threadIdx.x) * 4;
  int row = base >> 9;
  float m = mask[row];
  f32x4 ov = *(const f32x4*)(o1 + base);
  f32x4 xv = *(const f32x4*)(x + base);
#pragma unroll
  for (int j = 0; j < 4; ++j) xres[base + j] = xv[j] + ov[j] * m;
}

// ---------------- gated = silu(h1)*h3 -> bf16 ----------------
__global__ void ffngate_kernel(const float* __restrict__ h1, const float* __restrict__ h3,
                               __hip_bfloat16* __restrict__ g) {
  int base = (blockIdx.x * 256 + threadIdx.x) * 4;
  f32x4 a = *(const f32x4*)(h1 + base);
  f32x4 b3 = *(const f32x4*)(h3 + base);
#pragma unroll
  for (int j = 0; j < 4; ++j) {
    float v = a[j];
    float sil = v / (1.f + __expf(-v));
    g[base + j] = f2bf(sil * b3[j]);
  }
}

// ---------------- out = (xres + o2) * mask -> f32 ----------------
__global__ void final_kernel(const float* __restrict__ xres, const float* __restrict__ o2,
                             const float* __restrict__ mask, float* __restrict__ out) {
  int base = (blockIdx.x * 256 + threadIdx.x) * 4;
  int row = base >> 9;
  float m = mask[row];
  f32x4 xv = *(const f32x4*)(xres + base);
  f32x4 ov = *(const f32x4*)(o2 + base);
#pragma unroll
  for (int j = 0; j < 4; ++j) out[base + j] = (xv[j] + ov[j]) * m;
}

extern "C" void kernel_launch(void* const* d_in, const int* in_sizes, int n_in,
                              void* d_out, int out_size, void* d_ws, size_t ws_size,
                              hipStream_t stream) {
  const float* x    = (const float*)d_in[0];
  const float* mask = (const float*)d_in[1];
  const float* n1w  = (const float*)d_in[2];
  const float* n2w  = (const float*)d_in[3];
  const float* Wz   = (const float*)d_in[4];
  const float* Wx   = (const float*)d_in[5];
  const float* Wb   = (const float*)d_in[6];
  const float* Wc   = (const float*)d_in[7];
  const float* Wdt  = (const float*)d_in[8];
  const float* dtb  = (const float*)d_in[9];
  const float* Alog = (const float*)d_in[10];
  const float* Dsk  = (const float*)d_in[11];
  const float* Wout = (const float*)d_in[12];
  const float* w1   = (const float*)d_in[13];
  const float* w2   = (const float*)d_in[14];
  const float* w3   = (const float*)d_in[15];

  char* ws = (char*)d_ws;
  size_t off = 0;
  auto alloc = [&](size_t bytes) {
    char* p = ws + off;
    off += (bytes + 255) & ~(size_t)255;
    return p;
  };
  __hip_bfloat16* xnb = (__hip_bfloat16*)alloc((size_t)BSn * Dn * 2);
  float* xnf = (float*)alloc((size_t)BSn * Dn * 4);
  __hip_bfloat16* zb  = (__hip_bfloat16*)alloc((size_t)BSn * DINn * 2);
  __hip_bfloat16* ub  = (__hip_bfloat16*)alloc((size_t)BSn * DINn * 2);
  __hip_bfloat16* Bmb = (__hip_bfloat16*)alloc((size_t)BSn * 2048 * 2);
  __hip_bfloat16* Cmb = (__hip_bfloat16*)alloc((size_t)BSn * 2048 * 2);
  float* dt  = (float*)alloc((size_t)BSn * Hn * 4);
  float* la  = (float*)alloc((size_t)BSn * Hn * 4);
  float* ys  = (float*)alloc((size_t)BSn * DINn * 4);
  float* ecL = (float*)alloc((size_t)Bn * NCH * Hn * 4);
  float* ec  = (float*)alloc((size_t)Bn * NCH * Hn * 64 * 4);
  __hip_bfloat16* WzT   = (__hip_bfloat16*)alloc((size_t)DINn * Dn * 2);
  __hip_bfloat16* WxT   = (__hip_bfloat16*)alloc((size_t)DINn * Dn * 2);
  __hip_bfloat16* WbT   = (__hip_bfloat16*)alloc((size_t)2048 * Dn * 2);
  __hip_bfloat16* WcT   = (__hip_bfloat16*)alloc((size_t)2048 * Dn * 2);
  __hip_bfloat16* WoutT = (__hip_bfloat16*)alloc((size_t)Dn * DINn * 2);
  __hip_bfloat16* w1T   = (__hip_bfloat16*)alloc((size_t)DFFn * Dn * 2);
  __hip_bfloat16* w3T   = (__hip_bfloat16*)alloc((size_t)DFFn * Dn * 2);
  __hip_bfloat16* w2T   = (__hip_bfloat16*)alloc((size_t)Dn * DFFn * 2);
  // overlaid arena: scan-phase {Sbuf, Hp} then ffn-phase {y2b, o1, xres, h1, h3}
  char* arena = alloc(35000000);
  float* Sbuf = (float*)arena;                          // 16.8 MB (A->B)
  float* Hp   = (float*)(arena + 16777216);             // 16.8 MB (B->C)
  __hip_bfloat16* y2b = (__hip_bfloat16*)arena;         // 4 MB
  float* o1   = (float*)(arena + 4194304);              // 4 MB
  float* xres = (float*)(arena + 8388608);              // 4 MB
  float* h1   = (float*)(arena + 12582912);             // 11.2 MB
  float* h3   = (float*)(arena + 12582912 + 11206656);  // 11.2 MB
  __hip_bfloat16* gatedb = Bmb;                         // 5.6 MB <= 8 MB, dead after scan
  float* o2 = (float*)ub;                               // 4 MB, dead after gate

  dim3 tb(32, 8);
  transpose_kernel<<<dim3(32, 16), tb, 0, stream>>>(Wz, WzT, 512, 1024);
  transpose_kernel<<<dim3(32, 16), tb, 0, stream>>>(Wx, WxT, 512, 1024);
  transpose_kernel<<<dim3(64, 16), tb, 0, stream>>>(Wb, WbT, 512, 2048);
  transpose_kernel<<<dim3(64, 16), tb, 0, stream>>>(Wc, WcT, 512, 2048);
  transpose_kernel<<<dim3(16, 32), tb, 0, stream>>>(Wout, WoutT, 1024, 512);
  transpose_kernel<<<dim3(43, 16), tb, 0, stream>>>(w1, w1T, 512, 1368);
  transpose_kernel<<<dim3(43, 16), tb, 0, stream>>>(w3, w3T, 512, 1368);
  transpose_kernel<<<dim3(16, 43), tb, 0, stream>>>(w2, w2T, 1368, 512);

  rmsnorm1_kernel<<<BSn, 256, 0, stream>>>(x, n1w, mask, xnb, xnf);
  gemm_kernel<__hip_bfloat16><<<dim3(16, 8), 256, 0, stream>>>(xnb, WzT, zb, BSn, DINn, Dn);
  gemm_kernel<__hip_bfloat16><<<dim3(16, 8), 256, 0, stream>>>(xnb, WxT, ub, BSn, DINn, Dn);
  gemm_kernel<__hip_bfloat16><<<dim3(16, 16), 256, 0, stream>>>(xnb, WbT, Bmb, BSn, 2048, Dn);
  gemm_kernel<__hip_bfloat16><<<dim3(16, 16), 256, 0, stream>>>(xnb, WcT, Cmb, BSn, 2048, Dn);
  dt_kernel<<<BSn, 256, 0, stream>>>(xnf, Wdt, dtb, Alog, dt, la);
  chunk_intra_kernel<<<Bn * NCH * Hn, 256, 0, stream>>>(Bmb, Cmb, ub, dt, la, ys, Sbuf, ecL, ec);
  chunk_state_kernel<<<Bn * Hn * 32, 256, 0, stream>>>(Sbuf, ecL, Hp);
  chunk_inter_kernel<<<Bn * NCH * Hn, 256, 0, stream>>>(Cmb, Hp, ec, ys);
  gate_kernel<<<1024, 256, 0, stream>>>(ys, ub, zb, Dsk, y2b);
  gemm_kernel<float><<<dim3(16, 4), 256, 0, stream>>>(y2b, WoutT, o1, BSn, Dn, DINn);
  resid_kernel<<<1024, 256, 0, stream>>>(x, o1, mask, xres);
  rmsnorm2_kernel<<<BSn, 256, 0, stream>>>(xres, n2w, xnb);
  gemm_kernel<float><<<dim3(16, 11), 256, 0, stream>>>(xnb, w1T, h1, BSn, DFFn, Dn);
  gemm_kernel<float><<<dim3(16, 11), 256, 0, stream>>>(xnb, w3T, h3, BSn, DFFn, Dn);
  ffngate_kernel<<<2736, 256, 0, stream>>>(h1, h3, gatedb);
  gemm_kernel<float><<<dim3(16, 4), 256, 0, stream>>>(gatedb, w2T, o2, BSn, Dn, DFFn);
  final_kernel<<<1024, 256, 0, stream>>>(xres, o2, mask, (float*)d_out);
}

// Round 4
// 272.261 us; speedup vs baseline: 1.6922x; 1.2945x over previous
//
#include <hip/hip_runtime.h>
#include <hip/hip_bf16.h>
#include <math.h>
#include <type_traits>

#define Bn 4
#define Sn 512
#define Dn 512
#define DINn 1024
#define Hn 16
#define Pn 64
#define RNn 128
#define DFFn 1368
#define BSn (Bn*Sn)
#define CH 64
#define NCH (Sn/CH)   // 8
#define PSTR 6144     // fused proj row stride: [z(1024) | u(1024) | B(2048) | C(2048)]
#define FSTR 2736     // fused ffn row stride: [h1(1368) | h3(1368)]

typedef __attribute__((ext_vector_type(8))) short short8;
typedef __attribute__((ext_vector_type(4))) float f32x4;

static __device__ __forceinline__ float bf2f(__hip_bfloat16 v){return __bfloat162float(v);}
static __device__ __forceinline__ __hip_bfloat16 f2bf(float v){return __float2bfloat16(v);}
static __device__ __forceinline__ short f2bfs(float v){ __hip_bfloat16 b=f2bf(v); short s; __builtin_memcpy(&s,&b,2); return s; }
static __device__ __forceinline__ float bfs2f(short s){ __hip_bfloat16 b; __builtin_memcpy(&b,&s,2); return bf2f(b); }

// ---------------- transpose+cast: f32 [Rr x Cc] -> bf16 [Cc x Rr] ----------------
__global__ void transpose_kernel(const float* __restrict__ in,
                                 __hip_bfloat16* __restrict__ out, int Rr, int Cc) {
  __shared__ __hip_bfloat16 tile[32][33];
  int c0 = blockIdx.x * 32, r0 = blockIdx.y * 32;
  int tx = threadIdx.x, ty = threadIdx.y;
  for (int i = ty; i < 32; i += 8) {
    int r = r0 + i, cc = c0 + tx;
    tile[i][tx] = (r < Rr && cc < Cc) ? f2bf(in[(size_t)r * Cc + cc]) : f2bf(0.f);
  }
  __syncthreads();
  for (int i = ty; i < 32; i += 8) {
    int r = c0 + i, cc = r0 + tx;
    if (r < Cc && cc < Rr) out[(size_t)r * Rr + cc] = tile[tx][i];
  }
}

// ---------------- rmsnorm (f32 in) * mask -> bf16 + f32 ----------------
__global__ void rmsnorm1_kernel(const float* __restrict__ x,
                                const float* __restrict__ w,
                                const float* __restrict__ mask,
                                __hip_bfloat16* __restrict__ outb,
                                float* __restrict__ outf) {
  int row = blockIdx.x, t = threadIdx.x;
  const float* xr = x + (size_t)row * Dn;
  float v0 = xr[t], v1 = xr[t + 256];
  float ss = v0 * v0 + v1 * v1;
#pragma unroll
  for (int o = 32; o > 0; o >>= 1) ss += __shfl_down(ss, o);
  __shared__ float red[4];
  if ((t & 63) == 0) red[t >> 6] = ss;
  __syncthreads();
  float tot = red[0] + red[1] + red[2] + red[3];
  float sc = rsqrtf(tot * (1.f / Dn) + 1e-6f);
  sc *= mask[row];
  float o0 = v0 * sc * w[t], o1v = v1 * sc * w[t + 256];
  outb[(size_t)row * Dn + t] = f2bf(o0);
  outb[(size_t)row * Dn + t + 256] = f2bf(o1v);
  outf[(size_t)row * Dn + t] = o0;
  outf[(size_t)row * Dn + t + 256] = o1v;
}

// ---------------- rmsnorm (f32 in, no mask) -> bf16 ----------------
__global__ void rmsnorm2_kernel(const float* __restrict__ x,
                                const float* __restrict__ w,
                                __hip_bfloat16* __restrict__ out) {
  int row = blockIdx.x, t = threadIdx.x;
  const float* xr = x + (size_t)row * Dn;
  float v0 = xr[t], v1 = xr[t + 256];
  float ss = v0 * v0 + v1 * v1;
#pragma unroll
  for (int o = 32; o > 0; o >>= 1) ss += __shfl_down(ss, o);
  __shared__ float red[4];
  if ((t & 63) == 0) red[t >> 6] = ss;
  __syncthreads();
  float tot = red[0] + red[1] + red[2] + red[3];
  float sc = rsqrtf(tot * (1.f / Dn) + 1e-6f);
  out[(size_t)row * Dn + t] = f2bf(v0 * sc * w[t]);
  out[(size_t)row * Dn + t + 256] = f2bf(v1 * sc * w[t + 256]);
}

// ---------------- GEMM 128x128: C[M,N] = A[M,K] @ BT[N,K]^T, software-pipelined ----------------
template <typename OT>
__global__ __launch_bounds__(256) void gemm_kernel(
    const __hip_bfloat16* __restrict__ A, const __hip_bfloat16* __restrict__ BT,
    OT* __restrict__ C, int M, int N, int K) {
  __shared__ short As[128][40];
  __shared__ short Bs[128][40];
  int m0 = blockIdx.x * 128, n0 = blockIdx.y * 128;
  int t = threadIdx.x;
  int lane = t & 63, wv = t >> 6;
  int wm = (wv & 1) * 64, wn = (wv >> 1) * 64;
  f32x4 acc[4][4];
#pragma unroll
  for (int i = 0; i < 4; ++i)
#pragma unroll
    for (int j = 0; j < 4; ++j) acc[i][j] = (f32x4){0.f, 0.f, 0.f, 0.f};
  const short* Ag = (const short*)A;
  const short* Bg = (const short*)BT;
  int sr = t >> 2;
  int sc = (t & 3) * 8;
  int rb0 = n0 + sr, rb1 = n0 + sr + 64;
  bool bv0 = rb0 < N, bv1 = rb1 < N;
  const short* Ap0 = Ag + (size_t)(m0 + sr) * K + sc;
  const short* Ap1 = Ag + (size_t)(m0 + sr + 64) * K + sc;
  const short* Bp0 = Bg + (size_t)rb0 * K + sc;
  const short* Bp1 = Bg + (size_t)rb1 * K + sc;
  int kTiles = (K + 31) >> 5;
  short8 a0 = 0, a1 = 0, b0 = 0, b1 = 0;
  auto loadt = [&](int k0) {
    bool kin = (k0 + sc) < K;
    a0 = 0; a1 = 0; b0 = 0; b1 = 0;
    if (kin) {
      a0 = *(const short8*)(Ap0 + k0);
      a1 = *(const short8*)(Ap1 + k0);
      if (bv0) b0 = *(const short8*)(Bp0 + k0);
      if (bv1) b1 = *(const short8*)(Bp1 + k0);
    }
  };
  loadt(0);
  int fr = lane & 15, fq = (lane >> 4) * 8;
  for (int kt = 0; kt < kTiles; ++kt) {
    __syncthreads();
    *(short8*)&As[sr][sc] = a0;
    *(short8*)&As[sr + 64][sc] = a1;
    *(short8*)&Bs[sr][sc] = b0;
    *(short8*)&Bs[sr + 64][sc] = b1;
    __syncthreads();
    if (kt + 1 < kTiles) loadt((kt + 1) << 5);   // prefetch next tile; overlaps MFMA below
    short8 af[4], bfr[4];
#pragma unroll
    for (int i = 0; i < 4; ++i) af[i] = *(const short8*)&As[wm + i * 16 + fr][fq];
#pragma unroll
    for (int i = 0; i < 4; ++i) bfr[i] = *(const short8*)&Bs[wn + i * 16 + fr][fq];
#pragma unroll
    for (int mi = 0; mi < 4; ++mi)
#pragma unroll
      for (int ni = 0; ni < 4; ++ni)
        acc[mi][ni] = __builtin_amdgcn_mfma_f32_16x16x32_bf16(af[mi], bfr[ni], acc[mi][ni], 0, 0, 0);
  }
  int fq4 = (lane >> 4) * 4;
#pragma unroll
  for (int mi = 0; mi < 4; ++mi)
#pragma unroll
    for (int ni = 0; ni < 4; ++ni) {
      int col = n0 + wn + ni * 16 + fr;
      if (col < N) {
        int rowb = m0 + wm + mi * 16 + fq4;
#pragma unroll
        for (int r = 0; r < 4; ++r) {
          if constexpr (std::is_same<OT, float>::value)
            C[(size_t)(rowb + r) * N + col] = acc[mi][ni][r];
          else
            C[(size_t)(rowb + r) * N + col] = f2bf(acc[mi][ni][r]);
        }
      }
    }
}

// ---------------- GEMM 64x64 tile (for narrow-N GEMMs: more blocks -> more CUs) ----------------
template <typename OT>
__global__ __launch_bounds__(256) void gemm64_kernel(
    const __hip_bfloat16* __restrict__ A, const __hip_bfloat16* __restrict__ BT,
    OT* __restrict__ C, int M, int N, int K) {
  __shared__ short As[64][40];
  __shared__ short Bs[64][40];
  int m0 = blockIdx.x * 64, n0 = blockIdx.y * 64;
  int t = threadIdx.x;
  int lane = t & 63, wv = t >> 6;
  int wm = (wv & 1) * 32, wn = (wv >> 1) * 32;
  f32x4 acc[2][2];
#pragma unroll
  for (int i = 0; i < 2; ++i)
#pragma unroll
    for (int j = 0; j < 2; ++j) acc[i][j] = (f32x4){0.f, 0.f, 0.f, 0.f};
  const short* Ag = (const short*)A;
  const short* Bg = (const short*)BT;
  int sr = t >> 2;
  int sc = (t & 3) * 8;
  const short* Ap = Ag + (size_t)(m0 + sr) * K + sc;
  const short* Bp = Bg + (size_t)(n0 + sr) * K + sc;
  int kTiles = (K + 31) >> 5;
  short8 a0 = 0, b0 = 0;
  auto loadt = [&](int k0) {
    bool kin = (k0 + sc) < K;
    a0 = 0; b0 = 0;
    if (kin) {
      a0 = *(const short8*)(Ap + k0);
      b0 = *(const short8*)(Bp + k0);
    }
  };
  loadt(0);
  int fr = lane & 15, fq = (lane >> 4) * 8;
  for (int kt = 0; kt < kTiles; ++kt) {
    __syncthreads();
    *(short8*)&As[sr][sc] = a0;
    *(short8*)&Bs[sr][sc] = b0;
    __syncthreads();
    if (kt + 1 < kTiles) loadt((kt + 1) << 5);
    short8 af[2], bfr[2];
#pragma unroll
    for (int i = 0; i < 2; ++i) af[i] = *(const short8*)&As[wm + i * 16 + fr][fq];
#pragma unroll
    for (int i = 0; i < 2; ++i) bfr[i] = *(const short8*)&Bs[wn + i * 16 + fr][fq];
#pragma unroll
    for (int mi = 0; mi < 2; ++mi)
#pragma unroll
      for (int ni = 0; ni < 2; ++ni)
        acc[mi][ni] = __builtin_amdgcn_mfma_f32_16x16x32_bf16(af[mi], bfr[ni], acc[mi][ni], 0, 0, 0);
  }
  int fq4 = (lane >> 4) * 4;
#pragma unroll
  for (int mi = 0; mi < 2; ++mi)
#pragma unroll
    for (int ni = 0; ni < 2; ++ni) {
      int col = n0 + wn + ni * 16 + fr;
      int rowb = m0 + wm + mi * 16 + fq4;
#pragma unroll
      for (int r = 0; r < 4; ++r) {
        if constexpr (std::is_same<OT, float>::value)
          C[(size_t)(rowb + r) * N + col] = acc[mi][ni][r];
        else
          C[(size_t)(rowb + r) * N + col] = f2bf(acc[mi][ni][r]);
      }
    }
}

// ---------------- dt = softplus(xn @ Wdt + bias); la = -exp(A_log)*dt ----------------
__global__ void dt_kernel(const float* __restrict__ xnf,
                          const float* __restrict__ Wdt,
                          const float* __restrict__ dtb,
                          const float* __restrict__ Alog,
                          float* __restrict__ dt, float* __restrict__ la) {
  __shared__ float xs[Dn];
  int row = blockIdx.x, t = threadIdx.x;
  xs[t] = xnf[(size_t)row * Dn + t];
  xs[t + 256] = xnf[(size_t)row * Dn + t + 256];
  __syncthreads();
  int h = t >> 4, j = t & 15;
  float s = 0.f;
  for (int k = j * 32; k < j * 32 + 32; ++k) s = fmaf(xs[k], Wdt[k * Hn + h], s);
#pragma unroll
  for (int o = 8; o > 0; o >>= 1) s += __shfl_down(s, o, 16);
  if (j == 0) {
    float v = s + dtb[h];
    float sp = (v > 20.f) ? v : log1pf(expf(v));
    float Ah = expf(Alog[h]);
    dt[(size_t)row * Hn + h] = sp;
    la[(size_t)row * Hn + h] = -Ah * sp;
  }
}

// ---------------- chunked scan: intra-chunk + chunk-state ----------------
// block = (b, c, h); 256 threads = 4 waves. Reads u/B/C from fused P (stride PSTR).
__global__ __launch_bounds__(256) void chunk_intra_kernel(
    const __hip_bfloat16* __restrict__ P, const float* __restrict__ dt,
    const float* __restrict__ la, float* __restrict__ ys,
    float* __restrict__ Sbuf, float* __restrict__ ecL, float* __restrict__ ec) {
  int id = blockIdx.x;
  int h = id & 15, c = (id >> 4) & 7, b = id >> 7;
  int t = threadIdx.x, lane = t & 63, wv = t >> 6;
  __shared__ __align__(16) char smem[55040];
  short* sCB = (short*)smem;             // sC [64][136] (phase<=3a), sBt [128][72] (phase>=3b)
  short* sB  = (short*)(smem + 18432);   // [64][136]
  short* sUD = (short*)(smem + 35840);   // [64 p][72]  (s-minor)
  short* sG  = (short*)(smem + 45056);   // [64 t][72]  (s-minor)
  float* scum = (float*)(smem + 54272);  // [64]
  float* sws  = scum + 64;               // exp(cum63-cum[s])
  float* sdt  = sws + 64;
  int row0 = b * Sn + c * CH;
  const short* Pb = (const short*)P;
  // phase1: stage C,B (bf16), dt, la
#pragma unroll
  for (int i = 0; i < 4; ++i) {
    int idx = t + i * 256;               // 0..1023
    int r = idx >> 4, kc = (idx & 15) * 8;
    *(short8*)&sCB[r * 136 + kc] = *(const short8*)(Pb + (size_t)(row0 + r) * PSTR + 4096 + h * 128 + kc);
    *(short8*)&sB [r * 136 + kc] = *(const short8*)(Pb + (size_t)(row0 + r) * PSTR + 2048 + h * 128 + kc);
  }
  if (t < 64) { sdt[t] = dt[(size_t)(row0 + t) * Hn + h]; scum[t] = la[(size_t)(row0 + t) * Hn + h]; }
  __syncthreads();
  // phase2: wave0 log-space prefix; all waves build sUD (transposed u*dt)
  if (wv == 0) {
    float v = scum[lane];
#pragma unroll
    for (int o = 1; o < 64; o <<= 1) { float n = __shfl_up(v, o); if (lane >= o) v += n; }
    scum[lane] = v;
    float c63 = __shfl(v, 63);
    sws[lane] = __expf(c63 - v);
    ec[((size_t)((b * NCH + c) * Hn + h)) * 64 + lane] = __expf(v);
    if (lane == 0) ecL[(b * NCH + c) * Hn + h] = __expf(c63);
  }
#pragma unroll
  for (int i = 0; i < 2; ++i) {
    int idx = t + i * 256;               // 0..511
    int s = idx >> 3, pc = (idx & 7) * 8;
    short8 uv = *(const short8*)(Pb + (size_t)(row0 + s) * PSTR + 1024 + h * 64 + pc);
    float dv = sdt[s];
#pragma unroll
    for (int j = 0; j < 8; ++j) sUD[(pc + j) * 72 + s] = f2bfs(bfs2f(uv[j]) * dv);
  }
  __syncthreads();
  int fr = lane & 15, fq = (lane >> 4) * 8, q4 = (lane >> 4) * 4;
  // phase3a: G0 = C @ B^T (K=128), decay-mask, store bf16 sG
  {
    short8 af[4];
#pragma unroll
    for (int k = 0; k < 4; ++k) af[k] = *(short8*)&sCB[(16 * wv + fr) * 136 + k * 32 + fq];
#pragma unroll
    for (int j = 0; j < 4; ++j) {
      f32x4 acc = (f32x4){0.f, 0.f, 0.f, 0.f};
#pragma unroll
      for (int k = 0; k < 4; ++k) {
        short8 bf = *(short8*)&sB[(16 * j + fr) * 136 + k * 32 + fq];
        acc = __builtin_amdgcn_mfma_f32_16x16x32_bf16(af[k], bf, acc, 0, 0, 0);
      }
      int ss = 16 * j + fr;
      float cs = scum[ss];
#pragma unroll
      for (int r = 0; r < 4; ++r) {
        int tt = 16 * wv + q4 + r;
        float w = (ss <= tt) ? __expf(scum[tt] - cs) : 0.f;
        sG[tt * 72 + ss] = f2bfs(acc[r] * w);
      }
    }
  }
  __syncthreads();
  // phase3b: sBt[rn][s] = B[s][rn]*exp(cum63-cum[s])  (overwrites sC region)
#pragma unroll
  for (int i = 0; i < 32; ++i) {
    int idx = t + i * 256;
    int rn = idx >> 6, s = idx & 63;
    sCB[rn * 72 + s] = f2bfs(bfs2f(sB[s * 136 + rn]) * sws[s]);
  }
  __syncthreads();
  // phase4a: Y_intra = G @ UD  (M=64 t, N=64 p, K=64 s)
  {
    short8 ag[2];
#pragma unroll
    for (int k = 0; k < 2; ++k) ag[k] = *(short8*)&sG[(16 * wv + fr) * 72 + k * 32 + fq];
#pragma unroll
    for (int j = 0; j < 4; ++j) {
      f32x4 acc = (f32x4){0.f, 0.f, 0.f, 0.f};
#pragma unroll
      for (int k = 0; k < 2; ++k) {
        short8 bf = *(short8*)&sUD[(16 * j + fr) * 72 + k * 32 + fq];
        acc = __builtin_amdgcn_mfma_f32_16x16x32_bf16(ag[k], bf, acc, 0, 0, 0);
      }
#pragma unroll
      for (int r = 0; r < 4; ++r)
        ys[(size_t)(row0 + 16 * wv + q4 + r) * DINn + h * 64 + 16 * j + fr] = acc[r];
    }
  }
  // phase4b: S_c = Bt @ UD  (M=128 rn, N=64 p, K=64 s)
#pragma unroll
  for (int mt0 = 0; mt0 < 2; ++mt0) {
    int mt = wv * 2 + mt0;
    short8 ab[2];
#pragma unroll
    for (int k = 0; k < 2; ++k) ab[k] = *(short8*)&sCB[(16 * mt + fr) * 72 + k * 32 + fq];
#pragma unroll
    for (int j = 0; j < 4; ++j) {
      f32x4 acc = (f32x4){0.f, 0.f, 0.f, 0.f};
#pragma unroll
      for (int k = 0; k < 2; ++k) {
        short8 bf = *(short8*)&sUD[(16 * j + fr) * 72 + k * 32 + fq];
        acc = __builtin_amdgcn_mfma_f32_16x16x32_bf16(ab[k], bf, acc, 0, 0, 0);
      }
#pragma unroll
      for (int r = 0; r < 4; ++r)
        Sbuf[((size_t)((b * NCH + c) * Hn + h) * RNn + 16 * mt + q4 + r) * 64 + 16 * j + fr] = acc[r];
    }
  }
}

// ---------------- prefix over chunk states ----------------
__global__ void chunk_state_kernel(const float* __restrict__ Sbuf, const float* __restrict__ ecL,
                                   float* __restrict__ Hp) {
  int bh = blockIdx.x >> 5;                          // 64 (b,h) pairs
  int j = (blockIdx.x & 31) * 256 + threadIdx.x;     // 0..8191 = rn*64+p
  int b = bh >> 4, h = bh & 15;
  float hp = 0.f;
#pragma unroll
  for (int c = 0; c < NCH; ++c) {
    size_t addr = ((size_t)((b * NCH + c) * Hn + h)) * 8192 + j;
    Hp[addr] = hp;
    hp = ecL[(b * NCH + c) * Hn + h] * hp + Sbuf[addr];
  }
}

// ---------------- inter-chunk: ys += ecum[t] * (C @ H_prefix) ----------------
__global__ __launch_bounds__(256) void chunk_inter_kernel(
    const __hip_bfloat16* __restrict__ P, const float* __restrict__ Hp,
    const float* __restrict__ ec, float* __restrict__ ys) {
  int id = blockIdx.x;
  int h = id & 15, c = (id >> 4) & 7, b = id >> 7;
  if (c == 0) return;                                // Hp==0 for first chunk
  int t = threadIdx.x, lane = t & 63, wv = t >> 6;
  __shared__ __align__(16) short sC[64 * 136];
  __shared__ __align__(16) short sHt[64 * 136];      // [p][rn]
  __shared__ float sec[64];
  int row0 = b * Sn + c * CH;
  const short* Pb = (const short*)P;
  size_t hbase = ((size_t)((b * NCH + c) * Hn + h)) * 8192;
#pragma unroll
  for (int i = 0; i < 4; ++i) {
    int idx = t + i * 256;
    int r = idx >> 4, kc = (idx & 15) * 8;
    *(short8*)&sC[r * 136 + kc] = *(const short8*)(Pb + (size_t)(row0 + r) * PSTR + 4096 + h * 128 + kc);
  }
#pragma unroll
  for (int i = 0; i < 32; ++i) {
    int idx = t + i * 256;
    int rn = idx >> 6, p = idx & 63;
    sHt[p * 136 + rn] = f2bfs(Hp[hbase + idx]);
  }
  if (t < 64) sec[t] = ec[((size_t)((b * NCH + c) * Hn + h)) * 64 + t];
  __syncthreads();
  int fr = lane & 15, fq = (lane >> 4) * 8, q4 = (lane >> 4) * 4;
  short8 af[4];
#pragma unroll
  for (int k = 0; k < 4; ++k) af[k] = *(short8*)&sC[(16 * wv + fr) * 136 + k * 32 + fq];
#pragma unroll
  for (int j = 0; j < 4; ++j) {
    f32x4 acc = (f32x4){0.f, 0.f, 0.f, 0.f};
#pragma unroll
    for (int k = 0; k < 4; ++k) {
      short8 bf = *(short8*)&sHt[(16 * j + fr) * 136 + k * 32 + fq];
      acc = __builtin_amdgcn_mfma_f32_16x16x32_bf16(af[k], bf, acc, 0, 0, 0);
    }
#pragma unroll
    for (int r = 0; r < 4; ++r) {
      int tt = 16 * wv + q4 + r;
      size_t a = (size_t)(row0 + tt) * DINn + h * 64 + 16 * j + fr;
      ys[a] += sec[tt] * acc[r];
    }
  }
}

// ---------------- y2 = (ys + u*D_skip) * silu(z) -> bf16 ----------------
__global__ void gate_kernel(const float* __restrict__ ys, const __hip_bfloat16* __restrict__ P,
                            const float* __restrict__ Dsk, __hip_bfloat16* __restrict__ y2b) {
  int idx = (blockIdx.x * 256 + threadIdx.x) * 8;   // over BSn*DINn
  int row = idx >> 10, col = idx & 1023;
  const short* p = (const short*)P + (size_t)row * PSTR;
  short8 zv = *(const short8*)(p + col);
  short8 uv = *(const short8*)(p + 1024 + col);
  int h = col >> 6;
  float dsk = Dsk[h];
#pragma unroll
  for (int j = 0; j < 8; ++j) {
    float zz = bfs2f(zv[j]);
    float sil = zz / (1.f + __expf(-zz));
    y2b[idx + j] = f2bf((ys[idx + j] + bfs2f(uv[j]) * dsk) * sil);
  }
}

// ---------------- xres = x + o1*mask (f32 out) ----------------
__global__ void resid_kernel(const float* __restrict__ x, const float* __restrict__ o1,
                             const float* __restrict__ mask, float* __restrict__ xres) {
  int base = (blockIdx.x * 256 + threadIdx.x) * 4;
  int row = base >> 9;
  float m = mask[row];
  f32x4 ov = *(const f32x4*)(o1 + base);
  f32x4 xv = *(const f32x4*)(x + base);
#pragma unroll
  for (int j = 0; j < 4; ++j) xres[base + j] = xv[j] + ov[j] * m;
}

// ---------------- gated = silu(h1)*h3 from fused Hf (bf16) -> bf16 ----------------
__global__ void ffngate_kernel(const __hip_bfloat16* __restrict__ Hf,
                               __hip_bfloat16* __restrict__ g) {
  int row = blockIdx.x;
  int c8 = threadIdx.x;
  if (c8 >= DFFn / 8) return;
  int c = c8 * 8;
  const short* hrow = (const short*)Hf + (size_t)row * FSTR;
  short8 a = *(const short8*)(hrow + c);
  short8 b3 = *(const short8*)(hrow + DFFn + c);
  short8 o;
#pragma unroll
  for (int j = 0; j < 8; ++j) {
    float v = bfs2f(a[j]);
    float sil = v / (1.f + __expf(-v));
    o[j] = f2bfs(sil * bfs2f(b3[j]));
  }
  *(short8*)((short*)g + (size_t)row * DFFn + c) = o;
}

// ---------------- out = (xres + o2) * mask -> f32 ----------------
__global__ void final_kernel(const float* __restrict__ xres, const float* __restrict__ o2,
                             const float* __restrict__ mask, float* __restrict__ out) {
  int base = (blockIdx.x * 256 + threadIdx.x) * 4;
  int row = base >> 9;
  float m = mask[row];
  f32x4 xv = *(const f32x4*)(xres + base);
  f32x4 ov = *(const f32x4*)(o2 + base);
#pragma unroll
  for (int j = 0; j < 4; ++j) out[base + j] = (xv[j] + ov[j]) * m;
}

extern "C" void kernel_launch(void* const* d_in, const int* in_sizes, int n_in,
                              void* d_out, int out_size, void* d_ws, size_t ws_size,
                              hipStream_t stream) {
  const float* x    = (const float*)d_in[0];
  const float* mask = (const float*)d_in[1];
  const float* n1w  = (const float*)d_in[2];
  const float* n2w  = (const float*)d_in[3];
  const float* Wz   = (const float*)d_in[4];
  const float* Wx   = (const float*)d_in[5];
  const float* Wb   = (const float*)d_in[6];
  const float* Wc   = (const float*)d_in[7];
  const float* Wdt  = (const float*)d_in[8];
  const float* dtb  = (const float*)d_in[9];
  const float* Alog = (const float*)d_in[10];
  const float* Dsk  = (const float*)d_in[11];
  const float* Wout = (const float*)d_in[12];
  const float* w1   = (const float*)d_in[13];
  const float* w2   = (const float*)d_in[14];
  const float* w3   = (const float*)d_in[15];

  char* ws = (char*)d_ws;
  size_t off = 0;
  auto alloc = [&](size_t bytes) {
    char* p = ws + off;
    off += (bytes + 255) & ~(size_t)255;
    return p;
  };
  __hip_bfloat16* xnb = (__hip_bfloat16*)alloc((size_t)BSn * Dn * 2);
  float* xnf = (float*)alloc((size_t)BSn * Dn * 4);
  __hip_bfloat16* P = (__hip_bfloat16*)alloc((size_t)BSn * PSTR * 2);   // fused z|u|B|C
  float* dt  = (float*)alloc((size_t)BSn * Hn * 4);
  float* la  = (float*)alloc((size_t)BSn * Hn * 4);
  float* ys  = (float*)alloc((size_t)BSn * DINn * 4);
  float* ecL = (float*)alloc((size_t)Bn * NCH * Hn * 4);
  float* ec  = (float*)alloc((size_t)Bn * NCH * Hn * 64 * 4);
  __hip_bfloat16* WallT = (__hip_bfloat16*)alloc((size_t)PSTR * Dn * 2);     // [z|u|B|C]^T
  __hip_bfloat16* WoutT = (__hip_bfloat16*)alloc((size_t)Dn * DINn * 2);
  __hip_bfloat16* w13T  = (__hip_bfloat16*)alloc((size_t)FSTR * Dn * 2);     // [w1|w3]^T
  __hip_bfloat16* w2T   = (__hip_bfloat16*)alloc((size_t)Dn * DFFn * 2);
  // overlaid arena: scan-phase {Sbuf, Hp} then ffn-phase {y2b, o1, xres, Hf, gated, o2}
  char* arena = alloc(34000000);
  float* Sbuf = (float*)arena;                              // 16.78 MB
  float* Hp   = (float*)(arena + 16777216);                 // 16.78 MB
  __hip_bfloat16* y2b = (__hip_bfloat16*)arena;             // 4 MB
  float* o1   = (float*)(arena + 4194304);                  // 4 MB
  float* xres = (float*)(arena + 8388608);                  // 4 MB
  __hip_bfloat16* Hf = (__hip_bfloat16*)(arena + 12582912); // 11.2 MB fused h1|h3
  __hip_bfloat16* gatedb = (__hip_bfloat16*)(arena + 23789568); // 5.6 MB
  float* o2 = (float*)(arena + 29392896);                   // 4 MB

  dim3 tb(32, 8);
  transpose_kernel<<<dim3(32, 16), tb, 0, stream>>>(Wz, WallT, 512, 1024);
  transpose_kernel<<<dim3(32, 16), tb, 0, stream>>>(Wx, WallT + (size_t)1024 * 512, 512, 1024);
  transpose_kernel<<<dim3(64, 16), tb, 0, stream>>>(Wb, WallT + (size_t)2048 * 512, 512, 2048);
  transpose_kernel<<<dim3(64, 16), tb, 0, stream>>>(Wc, WallT + (size_t)4096 * 512, 512, 2048);
  transpose_kernel<<<dim3(16, 32), tb, 0, stream>>>(Wout, WoutT, 1024, 512);
  transpose_kernel<<<dim3(43, 16), tb, 0, stream>>>(w1, w13T, 512, 1368);
  transpose_kernel<<<dim3(43, 16), tb, 0, stream>>>(w3, w13T + (size_t)1368 * 512, 512, 1368);
  transpose_kernel<<<dim3(16, 43), tb, 0, stream>>>(w2, w2T, 1368, 512);

  rmsnorm1_kernel<<<BSn, 256, 0, stream>>>(x, n1w, mask, xnb, xnf);
  gemm_kernel<__hip_bfloat16><<<dim3(16, 48), 256, 0, stream>>>(xnb, WallT, P, BSn, PSTR, Dn);
  dt_kernel<<<BSn, 256, 0, stream>>>(xnf, Wdt, dtb, Alog, dt, la);
  chunk_intra_kernel<<<Bn * NCH * Hn, 256, 0, stream>>>(P, dt, la, ys, Sbuf, ecL, ec);
  chunk_state_kernel<<<Bn * Hn * 32, 256, 0, stream>>>(Sbuf, ecL, Hp);
  chunk_inter_kernel<<<Bn * NCH * Hn, 256, 0, stream>>>(P, Hp, ec, ys);
  gate_kernel<<<1024, 256, 0, stream>>>(ys, P, Dsk, y2b);
  gemm64_kernel<float><<<dim3(32, 8), 256, 0, stream>>>(y2b, WoutT, o1, BSn, Dn, DINn);
  resid_kernel<<<1024, 256, 0, stream>>>(x, o1, mask, xres);
  rmsnorm2_kernel<<<BSn, 256, 0, stream>>>(xres, n2w, xnb);
  gemm_kernel<__hip_bfloat16><<<dim3(16, 22), 256, 0, stream>>>(xnb, w13T, Hf, BSn, FSTR, Dn);
  ffngate_kernel<<<BSn, 192, 0, stream>>>(Hf, gatedb);
  gemm64_kernel<float><<<dim3(32, 8), 256, 0, stream>>>(gatedb, w2T, o2, BSn, Dn, DFFn);
  final_kernel<<<1024, 256, 0, stream>>>(xres, o2, mask, (float*)d_out);
}

// Round 5
// 243.360 us; speedup vs baseline: 1.8931x; 1.1188x over previous
//
#include <hip/hip_runtime.h>
#include <hip/hip_bf16.h>
#include <math.h>
#include <type_traits>

#define Bn 4
#define Sn 512
#define Dn 512
#define DINn 1024
#define Hn 16
#define Pn 64
#define RNn 128
#define DFFn 1368
#define BSn (Bn*Sn)
#define CH 64
#define NCH (Sn/CH)   // 8
#define PSTR 6144     // fused proj row stride: [z(1024) | u(1024) | B(2048) | C(2048)]
#define FSTR 2736     // fused ffn row stride: [h1(1368) | h3(1368)]

typedef __attribute__((ext_vector_type(8))) short short8;
typedef __attribute__((ext_vector_type(4))) float f32x4;

static __device__ __forceinline__ float bf2f(__hip_bfloat16 v){return __bfloat162float(v);}
static __device__ __forceinline__ __hip_bfloat16 f2bf(float v){return __float2bfloat16(v);}
static __device__ __forceinline__ short f2bfs(float v){ __hip_bfloat16 b=f2bf(v); short s; __builtin_memcpy(&s,&b,2); return s; }
static __device__ __forceinline__ float bfs2f(short s){ __hip_bfloat16 b; __builtin_memcpy(&b,&s,2); return bf2f(b); }

// ---------------- fused 8-way transpose+cast: f32 [Rr x Cc] -> bf16 [Cc x Rr] ----------------
struct T8 {
  const float* src[8];
  __hip_bfloat16* dst[8];
  int Rr[8], Cc[8], gw[8];
  int start[9];
};

__global__ void transpose8_kernel(T8 d) {
  int bid = blockIdx.x;
  int i = 0;
#pragma unroll
  for (int k = 1; k < 8; ++k) if (bid >= d.start[k]) i = k;
  int rel = bid - d.start[i];
  int gx = rel % d.gw[i], gy = rel / d.gw[i];
  const float* __restrict__ in = d.src[i];
  __hip_bfloat16* __restrict__ out = d.dst[i];
  int Rr = d.Rr[i], Cc = d.Cc[i];
  __shared__ __hip_bfloat16 tile[32][33];
  int c0 = gx * 32, r0 = gy * 32;
  int tx = threadIdx.x, ty = threadIdx.y;
  for (int k = ty; k < 32; k += 8) {
    int r = r0 + k, cc = c0 + tx;
    tile[k][tx] = (r < Rr && cc < Cc) ? f2bf(in[(size_t)r * Cc + cc]) : f2bf(0.f);
  }
  __syncthreads();
  for (int k = ty; k < 32; k += 8) {
    int r = c0 + k, cc = r0 + tx;
    if (r < Cc && cc < Rr) out[(size_t)r * Rr + cc] = tile[tx][k];
  }
}

// ---------------- rmsnorm1 * mask -> bf16, fused dt/la ----------------
__global__ void rmsnorm1_dt_kernel(const float* __restrict__ x,
                                   const float* __restrict__ w,
                                   const float* __restrict__ mask,
                                   const float* __restrict__ Wdt,
                                   const float* __restrict__ dtb,
                                   const float* __restrict__ Alog,
                                   __hip_bfloat16* __restrict__ outb,
                                   float* __restrict__ dt, float* __restrict__ la) {
  __shared__ float xs[Dn];
  __shared__ float red[4];
  int row = blockIdx.x, t = threadIdx.x;
  const float* xr = x + (size_t)row * Dn;
  float v0 = xr[t], v1 = xr[t + 256];
  float ss = v0 * v0 + v1 * v1;
#pragma unroll
  for (int o = 32; o > 0; o >>= 1) ss += __shfl_down(ss, o);
  if ((t & 63) == 0) red[t >> 6] = ss;
  __syncthreads();
  float tot = red[0] + red[1] + red[2] + red[3];
  float sc = rsqrtf(tot * (1.f / Dn) + 1e-6f) * mask[row];
  float o0 = v0 * sc * w[t], o1v = v1 * sc * w[t + 256];
  outb[(size_t)row * Dn + t] = f2bf(o0);
  outb[(size_t)row * Dn + t + 256] = f2bf(o1v);
  xs[t] = o0;
  xs[t + 256] = o1v;
  __syncthreads();
  int h = t >> 4, j = t & 15;
  float s = 0.f;
  for (int k = j * 32; k < j * 32 + 32; ++k) s = fmaf(xs[k], Wdt[k * Hn + h], s);
#pragma unroll
  for (int o = 8; o > 0; o >>= 1) s += __shfl_down(s, o, 16);
  if (j == 0) {
    float v = s + dtb[h];
    float sp = (v > 20.f) ? v : log1pf(expf(v));
    float Ah = expf(Alog[h]);
    dt[(size_t)row * Hn + h] = sp;
    la[(size_t)row * Hn + h] = -Ah * sp;
  }
}

// ---------------- rmsnorm (f32 in, no mask) -> bf16 ----------------
__global__ void rmsnorm2_kernel(const float* __restrict__ x,
                                const float* __restrict__ w,
                                __hip_bfloat16* __restrict__ out) {
  int row = blockIdx.x, t = threadIdx.x;
  const float* xr = x + (size_t)row * Dn;
  float v0 = xr[t], v1 = xr[t + 256];
  float ss = v0 * v0 + v1 * v1;
#pragma unroll
  for (int o = 32; o > 0; o >>= 1) ss += __shfl_down(ss, o);
  __shared__ float red[4];
  if ((t & 63) == 0) red[t >> 6] = ss;
  __syncthreads();
  float tot = red[0] + red[1] + red[2] + red[3];
  float sc = rsqrtf(tot * (1.f / Dn) + 1e-6f);
  out[(size_t)row * Dn + t] = f2bf(v0 * sc * w[t]);
  out[(size_t)row * Dn + t + 256] = f2bf(v1 * sc * w[t + 256]);
}

// ---------------- GEMM 128x128: C[M,N] = A[M,K] @ BT[N,K]^T, software-pipelined ----------------
template <typename OT>
__global__ __launch_bounds__(256) void gemm_kernel(
    const __hip_bfloat16* __restrict__ A, const __hip_bfloat16* __restrict__ BT,
    OT* __restrict__ C, int M, int N, int K) {
  __shared__ short As[128][40];
  __shared__ short Bs[128][40];
  int m0 = blockIdx.x * 128, n0 = blockIdx.y * 128;
  int t = threadIdx.x;
  int lane = t & 63, wv = t >> 6;
  int wm = (wv & 1) * 64, wn = (wv >> 1) * 64;
  f32x4 acc[4][4];
#pragma unroll
  for (int i = 0; i < 4; ++i)
#pragma unroll
    for (int j = 0; j < 4; ++j) acc[i][j] = (f32x4){0.f, 0.f, 0.f, 0.f};
  const short* Ag = (const short*)A;
  const short* Bg = (const short*)BT;
  int sr = t >> 2;
  int sc = (t & 3) * 8;
  int rb0 = n0 + sr, rb1 = n0 + sr + 64;
  bool bv0 = rb0 < N, bv1 = rb1 < N;
  const short* Ap0 = Ag + (size_t)(m0 + sr) * K + sc;
  const short* Ap1 = Ag + (size_t)(m0 + sr + 64) * K + sc;
  const short* Bp0 = Bg + (size_t)rb0 * K + sc;
  const short* Bp1 = Bg + (size_t)rb1 * K + sc;
  int kTiles = (K + 31) >> 5;
  short8 a0 = 0, a1 = 0, b0 = 0, b1 = 0;
  auto loadt = [&](int k0) {
    bool kin = (k0 + sc) < K;
    a0 = 0; a1 = 0; b0 = 0; b1 = 0;
    if (kin) {
      a0 = *(const short8*)(Ap0 + k0);
      a1 = *(const short8*)(Ap1 + k0);
      if (bv0) b0 = *(const short8*)(Bp0 + k0);
      if (bv1) b1 = *(const short8*)(Bp1 + k0);
    }
  };
  loadt(0);
  int fr = lane & 15, fq = (lane >> 4) * 8;
  for (int kt = 0; kt < kTiles; ++kt) {
    __syncthreads();
    *(short8*)&As[sr][sc] = a0;
    *(short8*)&As[sr + 64][sc] = a1;
    *(short8*)&Bs[sr][sc] = b0;
    *(short8*)&Bs[sr + 64][sc] = b1;
    __syncthreads();
    if (kt + 1 < kTiles) loadt((kt + 1) << 5);   // prefetch; overlaps MFMA
    short8 af[4], bfr[4];
#pragma unroll
    for (int i = 0; i < 4; ++i) af[i] = *(const short8*)&As[wm + i * 16 + fr][fq];
#pragma unroll
    for (int i = 0; i < 4; ++i) bfr[i] = *(const short8*)&Bs[wn + i * 16 + fr][fq];
#pragma unroll
    for (int mi = 0; mi < 4; ++mi)
#pragma unroll
      for (int ni = 0; ni < 4; ++ni)
        acc[mi][ni] = __builtin_amdgcn_mfma_f32_16x16x32_bf16(af[mi], bfr[ni], acc[mi][ni], 0, 0, 0);
  }
  int fq4 = (lane >> 4) * 4;
#pragma unroll
  for (int mi = 0; mi < 4; ++mi)
#pragma unroll
    for (int ni = 0; ni < 4; ++ni) {
      int col = n0 + wn + ni * 16 + fr;
      if (col < N) {
        int rowb = m0 + wm + mi * 16 + fq4;
#pragma unroll
        for (int r = 0; r < 4; ++r) {
          if constexpr (std::is_same<OT, float>::value)
            C[(size_t)(rowb + r) * N + col] = acc[mi][ni][r];
          else
            C[(size_t)(rowb + r) * N + col] = f2bf(acc[mi][ni][r]);
        }
      }
    }
}

// ---------------- GEMM 64x64 with fused epilogue ----------------
// MODE 1: out = aux + acc*mask[row]   (resid: xres = x + o1*mask)
// MODE 2: out = (aux + acc)*mask[row] (final: out = (xres + o2)*mask)
template <int MODE>
__global__ __launch_bounds__(256) void gemm64_ep_kernel(
    const __hip_bfloat16* __restrict__ A, const __hip_bfloat16* __restrict__ BT,
    const float* __restrict__ aux, const float* __restrict__ mask,
    float* __restrict__ out, int M, int N, int K) {
  __shared__ short As[64][40];
  __shared__ short Bs[64][40];
  int m0 = blockIdx.x * 64, n0 = blockIdx.y * 64;
  int t = threadIdx.x;
  int lane = t & 63, wv = t >> 6;
  int wm = (wv & 1) * 32, wn = (wv >> 1) * 32;
  f32x4 acc[2][2];
#pragma unroll
  for (int i = 0; i < 2; ++i)
#pragma unroll
    for (int j = 0; j < 2; ++j) acc[i][j] = (f32x4){0.f, 0.f, 0.f, 0.f};
  const short* Ag = (const short*)A;
  const short* Bg = (const short*)BT;
  int sr = t >> 2;
  int sc = (t & 3) * 8;
  const short* Ap = Ag + (size_t)(m0 + sr) * K + sc;
  const short* Bp = Bg + (size_t)(n0 + sr) * K + sc;
  int kTiles = (K + 31) >> 5;
  short8 a0 = 0, b0 = 0;
  auto loadt = [&](int k0) {
    bool kin = (k0 + sc) < K;
    a0 = 0; b0 = 0;
    if (kin) {
      a0 = *(const short8*)(Ap + k0);
      b0 = *(const short8*)(Bp + k0);
    }
  };
  loadt(0);
  int fr = lane & 15, fq = (lane >> 4) * 8;
  for (int kt = 0; kt < kTiles; ++kt) {
    __syncthreads();
    *(short8*)&As[sr][sc] = a0;
    *(short8*)&Bs[sr][sc] = b0;
    __syncthreads();
    if (kt + 1 < kTiles) loadt((kt + 1) << 5);
    short8 af[2], bfr[2];
#pragma unroll
    for (int i = 0; i < 2; ++i) af[i] = *(const short8*)&As[wm + i * 16 + fr][fq];
#pragma unroll
    for (int i = 0; i < 2; ++i) bfr[i] = *(const short8*)&Bs[wn + i * 16 + fr][fq];
#pragma unroll
    for (int mi = 0; mi < 2; ++mi)
#pragma unroll
      for (int ni = 0; ni < 2; ++ni)
        acc[mi][ni] = __builtin_amdgcn_mfma_f32_16x16x32_bf16(af[mi], bfr[ni], acc[mi][ni], 0, 0, 0);
  }
  int fq4 = (lane >> 4) * 4;
#pragma unroll
  for (int mi = 0; mi < 2; ++mi)
#pragma unroll
    for (int ni = 0; ni < 2; ++ni) {
      int col = n0 + wn + ni * 16 + fr;
#pragma unroll
      for (int r = 0; r < 4; ++r) {
        int row = m0 + wm + mi * 16 + fq4 + r;
        float m = mask[row];
        size_t a = (size_t)row * N + col;
        float v = acc[mi][ni][r];
        if constexpr (MODE == 1)
          out[a] = aux[a] + v * m;
        else
          out[a] = (aux[a] + v) * m;
      }
    }
}

// ---------------- chunked scan: intra-chunk + chunk-state ----------------
__global__ __launch_bounds__(256) void chunk_intra_kernel(
    const __hip_bfloat16* __restrict__ P, const float* __restrict__ dt,
    const float* __restrict__ la, float* __restrict__ ys,
    float* __restrict__ Sbuf, float* __restrict__ ecL, float* __restrict__ ec) {
  int id = blockIdx.x;
  int h = id & 15, c = (id >> 4) & 7, b = id >> 7;
  int t = threadIdx.x, lane = t & 63, wv = t >> 6;
  __shared__ __align__(16) char smem[55040];
  short* sCB = (short*)smem;             // sC [64][136] (phase<=3a), sBt [128][72] (phase>=3b)
  short* sB  = (short*)(smem + 18432);   // [64][136]
  short* sUD = (short*)(smem + 35840);   // [64 p][72]  (s-minor)
  short* sG  = (short*)(smem + 45056);   // [64 t][72]  (s-minor)
  float* scum = (float*)(smem + 54272);  // [64]
  float* sws  = scum + 64;               // exp(cum63-cum[s])
  float* sdt  = sws + 64;
  int row0 = b * Sn + c * CH;
  const short* Pb = (const short*)P;
#pragma unroll
  for (int i = 0; i < 4; ++i) {
    int idx = t + i * 256;
    int r = idx >> 4, kc = (idx & 15) * 8;
    *(short8*)&sCB[r * 136 + kc] = *(const short8*)(Pb + (size_t)(row0 + r) * PSTR + 4096 + h * 128 + kc);
    *(short8*)&sB [r * 136 + kc] = *(const short8*)(Pb + (size_t)(row0 + r) * PSTR + 2048 + h * 128 + kc);
  }
  if (t < 64) { sdt[t] = dt[(size_t)(row0 + t) * Hn + h]; scum[t] = la[(size_t)(row0 + t) * Hn + h]; }
  __syncthreads();
  if (wv == 0) {
    float v = scum[lane];
#pragma unroll
    for (int o = 1; o < 64; o <<= 1) { float n = __shfl_up(v, o); if (lane >= o) v += n; }
    scum[lane] = v;
    float c63 = __shfl(v, 63);
    sws[lane] = __expf(c63 - v);
    ec[((size_t)((b * NCH + c) * Hn + h)) * 64 + lane] = __expf(v);
    if (lane == 0) ecL[(b * NCH + c) * Hn + h] = __expf(c63);
  }
#pragma unroll
  for (int i = 0; i < 2; ++i) {
    int idx = t + i * 256;
    int s = idx >> 3, pc = (idx & 7) * 8;
    short8 uv = *(const short8*)(Pb + (size_t)(row0 + s) * PSTR + 1024 + h * 64 + pc);
    float dv = sdt[s];
#pragma unroll
    for (int j = 0; j < 8; ++j) sUD[(pc + j) * 72 + s] = f2bfs(bfs2f(uv[j]) * dv);
  }
  __syncthreads();
  int fr = lane & 15, fq = (lane >> 4) * 8, q4 = (lane >> 4) * 4;
  {
    short8 af[4];
#pragma unroll
    for (int k = 0; k < 4; ++k) af[k] = *(short8*)&sCB[(16 * wv + fr) * 136 + k * 32 + fq];
#pragma unroll
    for (int j = 0; j < 4; ++j) {
      f32x4 acc = (f32x4){0.f, 0.f, 0.f, 0.f};
#pragma unroll
      for (int k = 0; k < 4; ++k) {
        short8 bf = *(short8*)&sB[(16 * j + fr) * 136 + k * 32 + fq];
        acc = __builtin_amdgcn_mfma_f32_16x16x32_bf16(af[k], bf, acc, 0, 0, 0);
      }
      int ss = 16 * j + fr;
      float cs = scum[ss];
#pragma unroll
      for (int r = 0; r < 4; ++r) {
        int tt = 16 * wv + q4 + r;
        float w = (ss <= tt) ? __expf(scum[tt] - cs) : 0.f;
        sG[tt * 72 + ss] = f2bfs(acc[r] * w);
      }
    }
  }
  __syncthreads();
#pragma unroll
  for (int i = 0; i < 32; ++i) {
    int idx = t + i * 256;
    int rn = idx >> 6, s = idx & 63;
    sCB[rn * 72 + s] = f2bfs(bfs2f(sB[s * 136 + rn]) * sws[s]);
  }
  __syncthreads();
  {
    short8 ag[2];
#pragma unroll
    for (int k = 0; k < 2; ++k) ag[k] = *(short8*)&sG[(16 * wv + fr) * 72 + k * 32 + fq];
#pragma unroll
    for (int j = 0; j < 4; ++j) {
      f32x4 acc = (f32x4){0.f, 0.f, 0.f, 0.f};
#pragma unroll
      for (int k = 0; k < 2; ++k) {
        short8 bf = *(short8*)&sUD[(16 * j + fr) * 72 + k * 32 + fq];
        acc = __builtin_amdgcn_mfma_f32_16x16x32_bf16(ag[k], bf, acc, 0, 0, 0);
      }
#pragma unroll
      for (int r = 0; r < 4; ++r)
        ys[(size_t)(row0 + 16 * wv + q4 + r) * DINn + h * 64 + 16 * j + fr] = acc[r];
    }
  }
#pragma unroll
  for (int mt0 = 0; mt0 < 2; ++mt0) {
    int mt = wv * 2 + mt0;
    short8 ab[2];
#pragma unroll
    for (int k = 0; k < 2; ++k) ab[k] = *(short8*)&sCB[(16 * mt + fr) * 72 + k * 32 + fq];
#pragma unroll
    for (int j = 0; j < 4; ++j) {
      f32x4 acc = (f32x4){0.f, 0.f, 0.f, 0.f};
#pragma unroll
      for (int k = 0; k < 2; ++k) {
        short8 bf = *(short8*)&sUD[(16 * j + fr) * 72 + k * 32 + fq];
        acc = __builtin_amdgcn_mfma_f32_16x16x32_bf16(ab[k], bf, acc, 0, 0, 0);
      }
#pragma unroll
      for (int r = 0; r < 4; ++r)
        Sbuf[((size_t)((b * NCH + c) * Hn + h) * RNn + 16 * mt + q4 + r) * 64 + 16 * j + fr] = acc[r];
    }
  }
}

// ---------------- prefix over chunk states ----------------
__global__ void chunk_state_kernel(const float* __restrict__ Sbuf, const float* __restrict__ ecL,
                                   float* __restrict__ Hp) {
  int bh = blockIdx.x >> 5;
  int j = (blockIdx.x & 31) * 256 + threadIdx.x;
  int b = bh >> 4, h = bh & 15;
  float hp = 0.f;
#pragma unroll
  for (int c = 0; c < NCH; ++c) {
    size_t addr = ((size_t)((b * NCH + c) * Hn + h)) * 8192 + j;
    Hp[addr] = hp;
    hp = ecL[(b * NCH + c) * Hn + h] * hp + Sbuf[addr];
  }
}

// ---------------- inter-chunk + gate fused:
// y2 = (ys_intra + ecum[t]*(C @ Hp) + u*D_skip) * silu(z) -> bf16 ----------------
__global__ __launch_bounds__(256) void inter_gate_kernel(
    const __hip_bfloat16* __restrict__ P, const float* __restrict__ Hp,
    const float* __restrict__ ec, const float* __restrict__ ys,
    const float* __restrict__ Dsk, __hip_bfloat16* __restrict__ y2b) {
  int id = blockIdx.x;
  int h = id & 15, c = (id >> 4) & 7, b = id >> 7;
  int t = threadIdx.x, lane = t & 63, wv = t >> 6;
  __shared__ __align__(16) short sC[64 * 136];
  __shared__ __align__(16) short sHt[64 * 136];      // [p][rn]
  __shared__ __align__(16) short sz[64 * 64];
  __shared__ __align__(16) short su[64 * 64];
  __shared__ float sec[64];
  int row0 = b * Sn + c * CH;
  const short* Pb = (const short*)P;
#pragma unroll
  for (int i = 0; i < 2; ++i) {
    int idx = t + i * 256;
    int r = idx >> 3, pc = (idx & 7) * 8;
    *(short8*)&sz[r * 64 + pc] = *(const short8*)(Pb + (size_t)(row0 + r) * PSTR + h * 64 + pc);
    *(short8*)&su[r * 64 + pc] = *(const short8*)(Pb + (size_t)(row0 + r) * PSTR + 1024 + h * 64 + pc);
  }
  if (c > 0) {
    size_t hbase = ((size_t)((b * NCH + c) * Hn + h)) * 8192;
#pragma unroll
    for (int i = 0; i < 4; ++i) {
      int idx = t + i * 256;
      int r = idx >> 4, kc = (idx & 15) * 8;
      *(short8*)&sC[r * 136 + kc] = *(const short8*)(Pb + (size_t)(row0 + r) * PSTR + 4096 + h * 128 + kc);
    }
#pragma unroll
    for (int i = 0; i < 32; ++i) {
      int idx = t + i * 256;
      int rn = idx >> 6, p = idx & 63;
      sHt[p * 136 + rn] = f2bfs(Hp[hbase + idx]);
    }
    if (t < 64) sec[t] = ec[((size_t)((b * NCH + c) * Hn + h)) * 64 + t];
  }
  __syncthreads();
  int fr = lane & 15, fq = (lane >> 4) * 8, q4 = (lane >> 4) * 4;
  f32x4 acc[4];
#pragma unroll
  for (int j = 0; j < 4; ++j) acc[j] = (f32x4){0.f, 0.f, 0.f, 0.f};
  if (c > 0) {
    short8 af[4];
#pragma unroll
    for (int k = 0; k < 4; ++k) af[k] = *(short8*)&sC[(16 * wv + fr) * 136 + k * 32 + fq];
#pragma unroll
    for (int j = 0; j < 4; ++j)
#pragma unroll
      for (int k = 0; k < 4; ++k) {
        short8 bf = *(short8*)&sHt[(16 * j + fr) * 136 + k * 32 + fq];
        acc[j] = __builtin_amdgcn_mfma_f32_16x16x32_bf16(af[k], bf, acc[j], 0, 0, 0);
      }
  }
  float dsk = Dsk[h];
#pragma unroll
  for (int j = 0; j < 4; ++j) {
    int col = 16 * j + fr;
#pragma unroll
    for (int r = 0; r < 4; ++r) {
      int tt = 16 * wv + q4 + r;
      size_t a = (size_t)(row0 + tt) * DINn + h * 64 + col;
      float val = ys[a];
      if (c > 0) val += sec[tt] * acc[j][r];
      float uu = bfs2f(su[tt * 64 + col]);
      float zz = bfs2f(sz[tt * 64 + col]);
      float sil = zz / (1.f + __expf(-zz));
      y2b[a] = f2bf((val + uu * dsk) * sil);
    }
  }
}

// ---------------- gated = silu(h1)*h3 from fused Hf (bf16) -> bf16 ----------------
__global__ void ffngate_kernel(const __hip_bfloat16* __restrict__ Hf,
                               __hip_bfloat16* __restrict__ g) {
  int row = blockIdx.x;
  int c8 = threadIdx.x;
  if (c8 >= DFFn / 8) return;
  int c = c8 * 8;
  const short* hrow = (const short*)Hf + (size_t)row * FSTR;
  short8 a = *(const short8*)(hrow + c);
  short8 b3 = *(const short8*)(hrow + DFFn + c);
  short8 o;
#pragma unroll
  for (int j = 0; j < 8; ++j) {
    float v = bfs2f(a[j]);
    float sil = v / (1.f + __expf(-v));
    o[j] = f2bfs(sil * bfs2f(b3[j]));
  }
  *(short8*)((short*)g + (size_t)row * DFFn + c) = o;
}

extern "C" void kernel_launch(void* const* d_in, const int* in_sizes, int n_in,
                              void* d_out, int out_size, void* d_ws, size_t ws_size,
                              hipStream_t stream) {
  const float* x    = (const float*)d_in[0];
  const float* mask = (const float*)d_in[1];
  const float* n1w  = (const float*)d_in[2];
  const float* n2w  = (const float*)d_in[3];
  const float* Wz   = (const float*)d_in[4];
  const float* Wx   = (const float*)d_in[5];
  const float* Wb   = (const float*)d_in[6];
  const float* Wc   = (const float*)d_in[7];
  const float* Wdt  = (const float*)d_in[8];
  const float* dtb  = (const float*)d_in[9];
  const float* Alog = (const float*)d_in[10];
  const float* Dsk  = (const float*)d_in[11];
  const float* Wout = (const float*)d_in[12];
  const float* w1   = (const float*)d_in[13];
  const float* w2   = (const float*)d_in[14];
  const float* w3   = (const float*)d_in[15];

  char* ws = (char*)d_ws;
  size_t off = 0;
  auto alloc = [&](size_t bytes) {
    char* p = ws + off;
    off += (bytes + 255) & ~(size_t)255;
    return p;
  };
  __hip_bfloat16* xnb = (__hip_bfloat16*)alloc((size_t)BSn * Dn * 2);
  __hip_bfloat16* P = (__hip_bfloat16*)alloc((size_t)BSn * PSTR * 2);   // fused z|u|B|C
  float* dt  = (float*)alloc((size_t)BSn * Hn * 4);
  float* la  = (float*)alloc((size_t)BSn * Hn * 4);
  float* ys  = (float*)alloc((size_t)BSn * DINn * 4);
  float* ecL = (float*)alloc((size_t)Bn * NCH * Hn * 4);
  float* ec  = (float*)alloc((size_t)Bn * NCH * Hn * 64 * 4);
  __hip_bfloat16* WallT = (__hip_bfloat16*)alloc((size_t)PSTR * Dn * 2);     // [z|u|B|C]^T
  __hip_bfloat16* WoutT = (__hip_bfloat16*)alloc((size_t)Dn * DINn * 2);
  __hip_bfloat16* w13T  = (__hip_bfloat16*)alloc((size_t)FSTR * Dn * 2);     // [w1|w3]^T
  __hip_bfloat16* w2T   = (__hip_bfloat16*)alloc((size_t)Dn * DFFn * 2);
  // overlaid arena: scan-phase {Sbuf, Hp} then ffn-phase {y2b, xres, Hf, gated}
  char* arena = alloc(34000000);
  float* Sbuf = (float*)arena;                              // 16.78 MB, dead after chunk_state
  float* Hp   = (float*)(arena + 16777216);                 // 16.78 MB, dead after inter_gate
  __hip_bfloat16* y2b = (__hip_bfloat16*)arena;             // 4 MB (over dead Sbuf)
  float* xres = (float*)(arena + 8388608);                  // 4 MB
  __hip_bfloat16* Hf = (__hip_bfloat16*)(arena + 12582912); // 11.2 MB fused h1|h3 (over dead Hp tail)
  __hip_bfloat16* gatedb = (__hip_bfloat16*)(arena + 23789568); // 5.6 MB

  // -------- single fused transpose dispatch for all 8 weights --------
  T8 td;
  td.src[0] = Wz;   td.dst[0] = WallT;                        td.Rr[0] = 512;  td.Cc[0] = 1024;
  td.src[1] = Wx;   td.dst[1] = WallT + (size_t)1024 * 512;   td.Rr[1] = 512;  td.Cc[1] = 1024;
  td.src[2] = Wb;   td.dst[2] = WallT + (size_t)2048 * 512;   td.Rr[2] = 512;  td.Cc[2] = 2048;
  td.src[3] = Wc;   td.dst[3] = WallT + (size_t)4096 * 512;   td.Rr[3] = 512;  td.Cc[3] = 2048;
  td.src[4] = Wout; td.dst[4] = WoutT;                        td.Rr[4] = 1024; td.Cc[4] = 512;
  td.src[5] = w1;   td.dst[5] = w13T;                         td.Rr[5] = 512;  td.Cc[5] = 1368;
  td.src[6] = w3;   td.dst[6] = w13T + (size_t)1368 * 512;    td.Rr[6] = 512;  td.Cc[6] = 1368;
  td.src[7] = w2;   td.dst[7] = w2T;                          td.Rr[7] = 1368; td.Cc[7] = 512;
  int tot = 0;
  for (int i = 0; i < 8; ++i) {
    td.gw[i] = (td.Cc[i] + 31) / 32;
    int gh = (td.Rr[i] + 31) / 32;
    td.start[i] = tot;
    tot += td.gw[i] * gh;
  }
  td.start[8] = tot;   // 5648
  transpose8_kernel<<<tot, dim3(32, 8), 0, stream>>>(td);

  rmsnorm1_dt_kernel<<<BSn, 256, 0, stream>>>(x, n1w, mask, Wdt, dtb, Alog, xnb, dt, la);
  gemm_kernel<__hip_bfloat16><<<dim3(16, 48), 256, 0, stream>>>(xnb, WallT, P, BSn, PSTR, Dn);
  chunk_intra_kernel<<<Bn * NCH * Hn, 256, 0, stream>>>(P, dt, la, ys, Sbuf, ecL, ec);
  chunk_state_kernel<<<Bn * Hn * 32, 256, 0, stream>>>(Sbuf, ecL, Hp);
  inter_gate_kernel<<<Bn * NCH * Hn, 256, 0, stream>>>(P, Hp, ec, ys, Dsk, y2b);
  gemm64_ep_kernel<1><<<dim3(32, 8), 256, 0, stream>>>(y2b, WoutT, x, mask, xres, BSn, Dn, DINn);
  rmsnorm2_kernel<<<BSn, 256, 0, stream>>>(xres, n2w, xnb);
  gemm_kernel<__hip_bfloat16><<<dim3(16, 22), 256, 0, stream>>>(xnb, w13T, Hf, BSn, FSTR, Dn);
  ffngate_kernel<<<BSn, 192, 0, stream>>>(Hf, gatedb);
  gemm64_ep_kernel<2><<<dim3(32, 8), 256, 0, stream>>>(gatedb, w2T, xres, mask, (float*)d_out, BSn, Dn, DFFn);
}